// Round 9
// baseline (3620.684 us; speedup 1.0000x reference)
//
#include <hip/hip_runtime.h>
#include <cstdint>
#include <cmath>

// ---------------- dims ----------------
#define NB    64
#define EMBD  300
#define EMBP  320
#define EH    512
#define DH    1024
#define GV    23262
#define GVP   23296
#define TSRC  50
#define TDEC  49
#define GRIDN 248
#define LDS_SCR 131072
#define LDS_TOT (131072 + 16384 + 256)
#define FS    32      // ints between flags (128 B)

typedef __attribute__((ext_vector_type(8))) _Float16 f16x8;
typedef __attribute__((ext_vector_type(4))) float f32x4;

__device__ __forceinline__ float sigm(float x){ return 1.f/(1.f+expf(-x)); }

// ---- write-through (agent-scope relaxed atomic) stores, packed ----
__device__ __forceinline__ void cohS16(_Float16* p, _Float16 v){
  union { _Float16 f; unsigned short u; } c; c.f = v;
  __hip_atomic_store((unsigned short*)p, c.u, __ATOMIC_RELAXED, __HIP_MEMORY_SCOPE_AGENT);
}
__device__ __forceinline__ void cohS32(float* p, float v){
  __hip_atomic_store(p, v, __ATOMIC_RELAXED, __HIP_MEMORY_SCOPE_AGENT);
}
__device__ __forceinline__ void cohS64(void* p, unsigned long long v){
  __hip_atomic_store((unsigned long long*)p, v, __ATOMIC_RELAXED, __HIP_MEMORY_SCOPE_AGENT);
}
__device__ __forceinline__ void cohS32u(void* p, unsigned int v){
  __hip_atomic_store((unsigned int*)p, v, __ATOMIC_RELAXED, __HIP_MEMORY_SCOPE_AGENT);
}
__device__ __forceinline__ unsigned short h2u(float f){
  union { _Float16 h; unsigned short u; } c; c.h = (_Float16)f; return c.u;
}
__device__ __forceinline__ unsigned long long pk4h(float a, float b, float c, float d){
  return (unsigned long long)h2u(a) | ((unsigned long long)h2u(b)<<16)
       | ((unsigned long long)h2u(c)<<32) | ((unsigned long long)h2u(d)<<48);
}
__device__ __forceinline__ unsigned int pk2h(float a, float b){
  return (unsigned int)h2u(a) | ((unsigned int)h2u(b)<<16);
}
__device__ __forceinline__ unsigned long long pk2f(float a, float b){
  union { float f; unsigned int u; } x, y; x.f = a; y.f = b;
  return (unsigned long long)x.u | ((unsigned long long)y.u<<32);
}

// ---- flags ----
__device__ __forceinline__ int ldF(int* p){
  return __hip_atomic_load(p, __ATOMIC_RELAXED, __HIP_MEMORY_SCOPE_AGENT);
}
__device__ __forceinline__ void stF(int* p, int v){
  __hip_atomic_store(p, v, __ATOMIC_RELAXED, __HIP_MEMORY_SCOPE_AGENT);
}
// producer: drain stores (syncthreads waits vmcnt) then post own flag
__device__ __forceinline__ void post(int* flagArr, int idx, int epoch){
  __syncthreads();
  if (threadIdx.x == 0) stF(flagArr + idx*FS, epoch);
}
// consumer: poll ONE root flag, acquire-fence (inv L1/L2), proceed
__device__ __forceinline__ void waitRoot(int* root, int epoch){
  if (threadIdx.x == 0){
    while (ldF(root) < epoch) __builtin_amdgcn_s_sleep(2);
    __builtin_amdgcn_fence(__ATOMIC_ACQUIRE, "agent");
  }
  __syncthreads();
}

// ---- stage a [nrows][ncols] fp16 tile into LDS with XOR-16B swizzle ----
__device__ __forceinline__ void stageW(char* dst, const _Float16* __restrict__ src,
                                       int srcld, int nrows, int ncols, int tid)
{
  const int nch = ncols >> 3;
  for (int i = tid; i < nrows*nch; i += 256) {
    int row = i / nch, c = i - row*nch;
    *(f16x8*)(dst + row*ncols*2 + ((c*16) ^ ((row&7)<<4))) =
        *(const f16x8*)(src + (size_t)row*srcld + c*8);
  }
}

// 64x16 MFMA tile: acc += A[64][K](plain cached) @ B[16][K](LDS swizzled)^T
template<int K>
__device__ __forceinline__ void mm16L(f32x4 (&acc)[4],
    const _Float16* __restrict__ A, int lda,
    const char* ldsB, int rowbytes, int koffB, int lane)
{
  const int r = lane & 15, q = lane >> 4;
  const _Float16* a0 = A + r*lda + q*8;
  const char* b0 = ldsB + r*rowbytes + koffB;
  const int sw = (r & 7) << 4;
#pragma unroll
  for (int g = 0; g < K/256; ++g) {
    f16x8 av[8][4], bv[8];
#pragma unroll
    for (int s = 0; s < 8; ++s) {
      int sl = g*8 + s;
      bv[s] = *(const f16x8*)(b0 + ((sl*64 + q*16) ^ sw));
#pragma unroll
      for (int m = 0; m < 4; ++m)
        av[s][m] = *(const f16x8*)(a0 + m*16*lda + sl*32);
    }
#pragma unroll
    for (int s = 0; s < 8; ++s)
#pragma unroll
      for (int m = 0; m < 4; ++m)
        acc[m] = __builtin_amdgcn_mfma_f32_16x16x32_f16(av[s][m], bv[s], acc[m], 0, 0, 0);
  }
}

// ---------------- prep kernels ----------------
__global__ void cvt16s(const float* __restrict__ src, _Float16* __restrict__ dst,
                       int rows, int sld, int scols, int dcols)
{
  int idx = blockIdx.x*256 + threadIdx.x;
  if (idx >= rows*dcols) return;
  int c = idx % dcols, rr = idx / dcols;
  dst[idx] = (c < scols) ? (_Float16)src[(size_t)rr*sld + c] : (_Float16)0.f;
}

__global__ void addb(const float* __restrict__ a, const float* __restrict__ b,
                     float* __restrict__ o, int n)
{
  int i = blockIdx.x*256 + threadIdx.x;
  if (i < n) o[i] = a[i] + b[i];
}

__global__ void k_embed(const int* __restrict__ src, const int* __restrict__ trg,
                        const float* __restrict__ eemb, const float* __restrict__ demb,
                        _Float16* __restrict__ x_h, _Float16* __restrict__ xrev_h,
                        _Float16* __restrict__ pe_h)
{
  int idx = blockIdx.x*256 + threadIdx.x;
  const int tot1 = TSRC*NB*EMBP;
  const int tot2 = TDEC*NB*EMBP;
  if (idx < tot1) {
    int e = idx % EMBP, rb = idx / EMBP;
    int t = rb >> 6, b = rb & 63;
    float v = 0.f;
    if (e < EMBD) v = eemb[(size_t)src[rb]*EMBD + e];
    _Float16 hv = (_Float16)v;
    x_h[idx] = hv;
    xrev_h[(size_t)((TSRC-1-t)*NB + b)*EMBP + e] = hv;
  } else if (idx < tot1 + tot2) {
    int k = idx - tot1;
    int e = k % EMBP, rb = k / EMBP;
    float v = 0.f;
    if (e < EMBD) v = demb[(size_t)trg[rb]*EMBD + e];
    pe_h[k] = (_Float16)v;
  }
}

// ---------------- big tiled GEMM (throughput path), fp16 ----------------
__global__ __launch_bounds__(256) void gemm128(
    const _Float16* __restrict__ A, int lda,
    const _Float16* __restrict__ W, int ldw,
    const float* __restrict__ bias,
    float* __restrict__ out, int ldo,
    int K, int mvalid, int nvalid, int rowoff)
{
  __shared__ _Float16 As[128*64];
  __shared__ _Float16 Bs[128*64];
  const int tid = threadIdx.x;
  const int m0 = blockIdx.y*128, n0 = blockIdx.x*128;
  const int w = tid >> 6, lane = tid & 63, r = lane & 15, q = lane >> 4;
  const int mw = (w >> 1)*64, nw = (w & 1)*64;
  f32x4 acc[4][4];
#pragma unroll
  for (int mi=0; mi<4; ++mi)
#pragma unroll
    for (int ni=0; ni<4; ++ni) acc[mi][ni] = 0.f;

  for (int kt = 0; kt < K; kt += 64) {
    f16x8 ra[4], rb[4];
#pragma unroll
    for (int j = 0; j < 4; ++j) {
      int c = j*256 + tid, row = c >> 3, cc = c & 7;
      ra[j] = *(const f16x8*)(A + (size_t)(m0+row)*lda + kt + cc*8);
      rb[j] = *(const f16x8*)(W + (size_t)(n0+row)*ldw + kt + cc*8);
    }
    __syncthreads();
#pragma unroll
    for (int j = 0; j < 4; ++j) {
      int c = j*256 + tid, row = c >> 3, cc = c & 7;
      int sw = cc ^ (row & 7);
      *(f16x8*)((char*)As + row*128 + (sw<<4)) = ra[j];
      *(f16x8*)((char*)Bs + row*128 + (sw<<4)) = rb[j];
    }
    __syncthreads();
#pragma unroll
    for (int kk = 0; kk < 64; kk += 32) {
      int ch = (kk >> 3) + q;
      f16x8 av[4], bv[4];
#pragma unroll
      for (int mi=0; mi<4; ++mi) {
        int row = mw + mi*16 + r;
        av[mi] = *(const f16x8*)((char*)As + row*128 + ((ch ^ (row&7))<<4));
      }
#pragma unroll
      for (int ni=0; ni<4; ++ni) {
        int row = nw + ni*16 + r;
        bv[ni] = *(const f16x8*)((char*)Bs + row*128 + ((ch ^ (row&7))<<4));
      }
#pragma unroll
      for (int mi=0; mi<4; ++mi)
#pragma unroll
        for (int ni=0; ni<4; ++ni)
          acc[mi][ni] = __builtin_amdgcn_mfma_f32_16x16x32_f16(av[mi], bv[ni], acc[mi][ni], 0,0,0);
    }
  }
#pragma unroll
  for (int mi=0; mi<4; ++mi)
#pragma unroll
    for (int ni=0; ni<4; ++ni)
#pragma unroll
      for (int e=0; e<4; ++e) {
        int mrow = m0 + mw + mi*16 + q*4 + e;
        int col  = n0 + nw + ni*16 + r;
        if (mrow < mvalid && col < nvalid)
          out[(size_t)(mrow + rowoff)*ldo + col] = acc[mi][ni][e] + bias[col];
      }
}

// ---------------- persistent weight-stationary sequential kernel ----------------
struct SA {
  const _Float16 *whhF, *whhR;   // [2048][512]
  const _Float16 *wm1;           // [5120][1024] ([wi ; dWhh])
  const _Float16 *wo;            // [1024][2048]
  const _Float16 *w3c;           // [4096][1024]
  const float *xpF, *xpR;        // [50*64][2048]
  const float *pp;               // [49*64][4096]
  _Float16 *h;                   // [2 dir][2 buf][64][512]
  _Float16 *enc_out;             // [50][64][1024]
  _Float16 *dh;                  // [64][1024]
  float *dc;                     // [64][1024] (enc->dec handoff only)
  float *q;                      // [64][1024]
  float *gh;                     // [64][4096]
  _Float16 *st, *ct;             // [64][1024]
  _Float16 *hdec;                // [3200][1024]
  int *flags;
};

// WG roles: 0-31 enc-f + P1q + P2 | 32-63 enc-r + P2 | 64-191 gh + P4 |
// 192-223 P3 (dh-part prefolded) | 224 chain combiner | 225 FG combiner |
// 226/227 enc combiners | 228+ exit.
__global__ __launch_bounds__(256, 1) void seq_kernel(SA a)
{
  extern __shared__ char lds[];
  const int tid = threadIdx.x, w = tid >> 6, lane = tid & 63;
  const int wgid = blockIdx.x;
  const int r = lane & 15, q4 = lane >> 4;
  float (*sm4)[64][16] = (float(*)[64][16])(lds + LDS_SCR);
  float* qs = (float*)(lds + LDS_SCR);
  float* sc = (float*)(lds + LDS_SCR + 16384);

  int* FE = a.flags;              // 64
  int* FA = FE + 64*FS;           // 32
  int* FB = FA + 32*FS;           // 64
  int* FC = FB + 64*FS;           // 32
  int* FD = FC + 32*FS;           // 128
  int* FG = FD + 128*FS;          // 128
  int* RT = FG + 128*FS;          // roots: Ef, Er, A, B, C, D, G
  int *R_Ef = RT, *R_Er = RT+FS, *R_A = RT+2*FS, *R_B = RT+3*FS,
      *R_C = RT+4*FS, *R_D = RT+5*FS, *R_G = RT+6*FS;

  if (wgid >= 224) {
    if (wgid == 224) {               // decoder chain combiner
      for (int t = 1; t <= TDEC; ++t) {
        if (tid < 32)  { int* p = FA + tid*FS; while (ldF(p) < t) __builtin_amdgcn_s_sleep(2); }
        __syncthreads();
        if (tid == 0) stF(R_A, t);
        if (tid < 64)  { int* p = FB + tid*FS; while (ldF(p) < t) __builtin_amdgcn_s_sleep(2); }
        __syncthreads();
        if (tid == 0) stF(R_B, t);
        if (tid < 32)  { int* p = FC + tid*FS; while (ldF(p) < t) __builtin_amdgcn_s_sleep(2); }
        __syncthreads();
        if (tid == 0) stF(R_C, t);
        if (tid < 128) { int* p = FD + tid*FS; while (ldF(p) < t) __builtin_amdgcn_s_sleep(2); }
        __syncthreads();
        if (tid == 0) stF(R_D, t);
      }
    } else if (wgid == 225) {        // gh combiner
      for (int t = 1; t <= TDEC; ++t) {
        if (tid < 128) { int* p = FG + tid*FS; while (ldF(p) < t) __builtin_amdgcn_s_sleep(2); }
        __syncthreads();
        if (tid == 0) stF(R_G, t);
      }
    } else if (wgid == 226 || wgid == 227) {   // encoder combiners
      int* base = FE + (wgid - 226)*32*FS;
      int* root = (wgid == 226) ? R_Ef : R_Er;
      for (int e = 1; e <= TSRC; ++e) {
        if (tid < 32) { int* p = base + tid*FS; while (ldF(p) < e) __builtin_amdgcn_s_sleep(2); }
        __syncthreads();
        if (tid == 0) stF(root, e);
      }
    }
    return;
  }

  // ---- stage weights into LDS ----
  if (wgid < 64) {
    int dir = wgid >> 5, j0 = (wgid & 31) << 4;
    const _Float16* whh = dir ? a.whhR : a.whhF;
    for (int g = 0; g < 4; ++g)
      stageW(lds + g*16384, whh + (size_t)(g*EH + j0)*EH, EH, 16, 512, tid);
    if (wgid < 32)
      stageW(lds + 65536, a.wm1 + (size_t)wgid*32*DH, DH, 32, 1024, tid);
  } else if (wgid < 192) {
    int i = wgid - 64;
    stageW(lds, a.wm1 + (size_t)(1024 + i*32)*DH, DH, 32, 1024, tid);           // gh unit
    for (int g = 0; g < 4; ++g)                                                  // P4 unit
      stageW(lds + 65536 + g*8*2048, a.w3c + (size_t)(g*1024 + i*8)*DH, DH, 8, 1024, tid);
  } else {
    int i = wgid - 192;
    stageW(lds,         a.wo + (size_t)i*32*2048,        2048, 32, 1024, tid);  // st-part
    stageW(lds + 65536, a.wo + (size_t)i*32*2048 + 1024, 2048, 32, 1024, tid);  // dh-part
  }
  __syncthreads();

  // ================= encoder (WGs 0-63) =================
  if (wgid < 64) {
    const int dir = wgid >> 5, j0 = (wgid & 31) << 4;
    const int b = tid >> 2, jq = (tid & 3) * 4;
    float creg[4] = {0.f, 0.f, 0.f, 0.f};
    const float* xpbase = dir ? a.xpR : a.xpF;
    int* myRoot = dir ? R_Er : R_Ef;
    for (int t = 0; t < TSRC; ++t) {
      // prefetch xp (read-only) BEFORE the wait
      float xr[4][4];
#pragma unroll
      for (int g = 0; g < 4; ++g)
#pragma unroll
        for (int k = 0; k < 4; ++k)
          xr[g][k] = xpbase[((size_t)t*NB + b)*2048 + g*EH + j0 + jq + k];
      if (t) waitRoot(myRoot, t);
      const int cur = t & 1;
      const _Float16* H = a.h + (size_t)(dir*2 + cur)*NB*EH;
      f32x4 acc[4];
#pragma unroll
      for (int m=0;m<4;++m) acc[m] = 0.f;
      mm16L<EH>(acc, H, EH, lds + w*16384, 1024, 0, lane);
#pragma unroll
      for (int m=0;m<4;++m)
#pragma unroll
        for (int e=0;e<4;++e) sm4[w][m*16 + q4*4 + e][r] = acc[m][e];
      __syncthreads();
      _Float16* Ho = a.h + (size_t)(dir*2 + (cur^1))*NB*EH;
      const int erow = dir ? (TSRC-1 - t) : t;
      float hv[4];
#pragma unroll
      for (int k = 0; k < 4; ++k) {
        int jj = jq + k;
        float gi = sm4[0][b][jj] + xr[0][k];
        float gf = sm4[1][b][jj] + xr[1][k];
        float gg = sm4[2][b][jj] + xr[2][k];
        float go = sm4[3][b][jj] + xr[3][k];
        float cn = sigm(gf)*creg[k] + sigm(gi)*tanhf(gg);
        creg[k] = cn;
        hv[k] = sigm(go)*tanhf(cn);
      }
      cohS64(Ho + b*EH + j0 + jq, pk4h(hv[0],hv[1],hv[2],hv[3]));
      cohS64(a.enc_out + ((size_t)erow*NB + b)*DH + dir*EH + j0 + jq, pk4h(hv[0],hv[1],hv[2],hv[3]));
      if (t == TSRC-1) {
#pragma unroll
        for (int k = 0; k < 4; ++k) {
          int j = j0 + jq + k;
          cohS16(a.dh + b*DH + 2*j + dir, (_Float16)hv[k]);
          cohS32(a.dc + b*DH + 2*j + dir, creg[k]);
        }
      }
      post(FE, wgid, t+1);
      __syncthreads();
    }
  }

  // ================= decoder =================
  const bool isA  = (wgid < 32);
  const bool isP2 = (wgid < 64);
  const bool isBD = (wgid >= 64 && wgid < 192);
  const bool isC  = (wgid >= 192);

  float dcreg[2] = {0.f, 0.f};

  for (int t = 0; t < TDEC; ++t) {
    // ---- A: q = dh @ wi^T (WGs 0-31) ----
    if (isA) {
      if (t == 0) { waitRoot(R_Ef, TSRC); waitRoot(R_Er, TSRC); }
      else        waitRoot(R_D, t);
      const int col0 = wgid*32;
      const int cs = w >> 1, kh = w & 1;
      f32x4 acc[4];
#pragma unroll
      for (int m=0;m<4;++m) acc[m] = 0.f;
      mm16L<512>(acc, a.dh + kh*512, DH, lds + 65536 + cs*16*2048, 2048, kh*1024, lane);
#pragma unroll
      for (int m=0;m<4;++m)
#pragma unroll
        for (int e=0;e<4;++e) sm4[w][m*16 + q4*4 + e][r] = acc[m][e];
      __syncthreads();
      const int b = tid >> 2, cc0 = (tid & 3)*8;
#pragma unroll
      for (int k = 0; k < 8; k += 2) {
        int c1 = cc0 + k, c2 = c1 + 1;
        float v1 = sm4[(c1>>4)*2][b][c1&15] + sm4[(c1>>4)*2+1][b][c1&15];
        float v2 = sm4[(c2>>4)*2][b][c2&15] + sm4[(c2>>4)*2+1][b][c2&15];
        cohS64(a.q + b*DH + col0 + c1, pk2f(v1, v2));
      }
      post(FA, wgid, t+1);
    }

    // ---- P2: attention (WGs 0-63) ----
    if (isP2) {
      waitRoot(R_A, t+1);
      const int b = wgid;
      { f32x4* qv = (f32x4*)qs;
        qv[tid] = *(const f32x4*)(a.q + b*DH + tid*4); }
      __syncthreads();
      for (int tt = w; tt < TSRC; tt += 4) {
        const _Float16* er = a.enc_out + ((size_t)tt*NB + b)*DH + lane*16;
        const float* qq = qs + lane*16;
        f16x8 e0 = *(const f16x8*)(er);
        f16x8 e1 = *(const f16x8*)(er + 8);
        float s = 0.f;
#pragma unroll
        for (int ii=0; ii<8; ++ii) s += (float)e0[ii]*qq[ii];
#pragma unroll
        for (int ii=0; ii<8; ++ii) s += (float)e1[ii]*qq[8+ii];
#pragma unroll
        for (int o=32; o; o>>=1) s += __shfl_xor(s, o);
        if (lane == 0) sc[tt] = s;
      }
      __syncthreads();
      float mx = -1e30f;
      for (int tt=0; tt<TSRC; ++tt) mx = fmaxf(mx, sc[tt]);
      __syncthreads();
      if (tid < TSRC) sc[tid] = expf(sc[tid] - mx);
      __syncthreads();
      float s50 = 0.f;
      for (int tt=0; tt<TSRC; ++tt) s50 += sc[tt];
      const float inv = 1.f/s50;
      const int c0 = tid*4;
      float a0=0.f, a1=0.f, a2=0.f, a3=0.f;
      for (int tt=0; tt<TSRC; ++tt) {
        float wt = sc[tt];
        const _Float16* er = a.enc_out + ((size_t)tt*NB + b)*DH + c0;
        a0 += wt*(float)er[0]; a1 += wt*(float)er[1];
        a2 += wt*(float)er[2]; a3 += wt*(float)er[3];
      }
      cohS64(a.st + b*DH + c0, pk4h(a0*inv, a1*inv, a2*inv, a3*inv));
      post(FB, wgid, t+1);
    }

    // ---- C: ct = tanh(st@woA + dh@woB) (WGs 192-223); dh-part off critical path ----
    if (isC) {
      if (t == 0) { waitRoot(R_Ef, TSRC); waitRoot(R_Er, TSRC); }
      else        waitRoot(R_D, t);
      const int col0 = (wgid - 192)*32;
      const int cs = w >> 1, kh = w & 1;
      f32x4 acc[4];
#pragma unroll
      for (int m=0;m<4;++m) acc[m] = 0.f;
      mm16L<512>(acc, a.dh + kh*512, DH, lds + 65536 + cs*16*2048, 2048, kh*1024, lane);  // dh-part
      waitRoot(R_B, t+1);
      mm16L<512>(acc, a.st + kh*512, DH, lds + cs*16*2048, 2048, kh*1024, lane);          // st-part
#pragma unroll
      for (int m=0;m<4;++m)
#pragma unroll
        for (int e=0;e<4;++e) sm4[w][m*16 + q4*4 + e][r] = acc[m][e];
      __syncthreads();
      const int b = tid >> 2, cc0 = (tid & 3)*8;
      float v[8];
#pragma unroll
      for (int k = 0; k < 8; ++k) {
        int cc = cc0 + k;
        v[k] = tanhf(sm4[(cc>>4)*2][b][cc&15] + sm4[(cc>>4)*2+1][b][cc&15]);
      }
      cohS64(a.ct + b*DH + col0 + cc0,     pk4h(v[0],v[1],v[2],v[3]));
      cohS64(a.ct + b*DH + col0 + cc0 + 4, pk4h(v[4],v[5],v[6],v[7]));
      post(FC, wgid - 192, t+1);
    }

    // ---- B then D (WGs 64-191): gh = dh@dWhh^T, then P4 gates+LSTM ----
    if (isBD) {
      const int i = wgid - 64;
      if (t == 0) { waitRoot(R_Ef, TSRC); waitRoot(R_Er, TSRC); }
      else        waitRoot(R_D, t);
      const int b = tid >> 2;
      const int j0 = i*8, jj2 = (tid & 3)*2;
      if (t == 0) {   // load cell state into regs (written by encoder)
        dcreg[0] = a.dc[b*DH + j0 + jj2];
        dcreg[1] = a.dc[b*DH + j0 + jj2 + 1];
      }
      {  // B: gh unit (32 cols)
        const int col0 = i*32;
        const int cs = w >> 1, kh = w & 1;
        f32x4 acc[4];
#pragma unroll
        for (int m=0;m<4;++m) acc[m] = 0.f;
        mm16L<512>(acc, a.dh + kh*512, DH, lds + cs*16*2048, 2048, kh*1024, lane);
#pragma unroll
        for (int m=0;m<4;++m)
#pragma unroll
          for (int e=0;e<4;++e) sm4[w][m*16 + q4*4 + e][r] = acc[m][e];
        __syncthreads();
        const int cc0 = (tid & 3)*8;
#pragma unroll
        for (int k = 0; k < 8; k += 2) {
          int c1 = cc0 + k, c2 = c1 + 1;
          float v1 = sm4[(c1>>4)*2][b][c1&15] + sm4[(c1>>4)*2+1][b][c1&15];
          float v2 = sm4[(c2>>4)*2][b][c2&15] + sm4[(c2>>4)*2+1][b][c2&15];
          cohS64(a.gh + (size_t)b*4096 + col0 + c1, pk2f(v1, v2));
        }
        post(FG, i, t+1);
      }
      // prefetch pp (read-only) while P2/P3 run
      float ppv[4][2];
#pragma unroll
      for (int g = 0; g < 4; ++g)
#pragma unroll
        for (int k = 0; k < 2; ++k)
          ppv[g][k] = a.pp[((size_t)t*NB + b)*4096 + g*DH + j0 + jj2 + k];
      // gh prefetch after all gh producers done
      waitRoot(R_G, t+1);
      float ghv[4][2];
#pragma unroll
      for (int g = 0; g < 4; ++g)
#pragma unroll
        for (int k = 0; k < 2; ++k)
          ghv[g][k] = a.gh[(size_t)b*4096 + g*DH + j0 + jj2 + k];
      // D: gates = ct @ w3 + gh + pp; LSTM
      waitRoot(R_C, t+1);
      {
        const int cs = w >> 1, kh = w & 1;
        f32x4 acc[4];
#pragma unroll
        for (int m=0;m<4;++m) acc[m] = 0.f;
        mm16L<512>(acc, a.ct + kh*512, DH, lds + 65536 + cs*16*2048, 2048, kh*1024, lane);
#pragma unroll
        for (int m=0;m<4;++m)
#pragma unroll
          for (int e=0;e<4;++e) sm4[w][m*16 + q4*4 + e][r] = acc[m][e];
        __syncthreads();
        float hv[2];
#pragma unroll
        for (int k = 0; k < 2; ++k) {
          int jj = jj2 + k;
          float gi = sm4[0][b][jj]   + sm4[1][b][jj]   + ghv[0][k] + ppv[0][k];
          float gf = sm4[0][b][8+jj] + sm4[1][b][8+jj] + ghv[1][k] + ppv[1][k];
          float gg = sm4[2][b][jj]   + sm4[3][b][jj]   + ghv[2][k] + ppv[2][k];
          float go = sm4[2][b][8+jj] + sm4[3][b][8+jj] + ghv[3][k] + ppv[3][k];
          float cn = sigm(gf)*dcreg[k] + sigm(gi)*tanhf(gg);
          dcreg[k] = cn;
          hv[k] = sigm(go)*tanhf(cn);
        }
        cohS32u(a.dh + b*DH + j0 + jj2, pk2h(hv[0], hv[1]));
        cohS32u(a.hdec + ((size_t)t*NB + b)*DH + j0 + jj2, pk2h(hv[0], hv[1]));
        post(FD, i, t+1);
      }
    }
  }
}

// ---------------- in-place log-softmax over vocab rows ----------------
__global__ __launch_bounds__(256) void lsm(float* __restrict__ out)
{
  const int row = NB + blockIdx.x;
  float* p = out + (size_t)row*GV;
  const int tid = threadIdx.x;
  __shared__ float red[4], red2[4];
  float mx = -1e30f;
  for (int i = tid; i < GV; i += 256) mx = fmaxf(mx, p[i]);
  for (int off=32; off; off>>=1) mx = fmaxf(mx, __shfl_down(mx, off));
  if ((tid & 63) == 0) red[tid>>6] = mx;
  __syncthreads();
  mx = fmaxf(fmaxf(red[0],red[1]), fmaxf(red[2],red[3]));
  float sm = 0.f;
  for (int i = tid; i < GV; i += 256) sm += expf(p[i] - mx);
  for (int off=32; off; off>>=1) sm += __shfl_down(sm, off);
  if ((tid & 63) == 0) red2[tid>>6] = sm;
  __syncthreads();
  sm = red2[0]+red2[1]+red2[2]+red2[3];
  float lse = mx + logf(sm);
  for (int i = tid; i < GV; i += 256) p[i] -= lse;
}

// ---------------- host ----------------
extern "C" void kernel_launch(void* const* d_in, const int* in_sizes, int n_in,
                              void* d_out, int out_size, void* d_ws, size_t ws_size,
                              hipStream_t stream)
{
  const int*   src  = (const int*)d_in[0];
  const int*   trg  = (const int*)d_in[1];
  const float* WihF = (const float*)d_in[2];
  const float* WhhF = (const float*)d_in[3];
  const float* bihF = (const float*)d_in[4];
  const float* bhhF = (const float*)d_in[5];
  const float* WihR = (const float*)d_in[6];
  const float* WhhR = (const float*)d_in[7];
  const float* bihR = (const float*)d_in[8];
  const float* bhhR = (const float*)d_in[9];
  const float* dWih = (const float*)d_in[10];
  const float* dWhh = (const float*)d_in[11];
  const float* dbih = (const float*)d_in[12];
  const float* dbhh = (const float*)d_in[13];
  const float* eemb = (const float*)d_in[14];
  const float* demb = (const float*)d_in[15];
  const float* wi   = (const float*)d_in[16];
  const float* wo   = (const float*)d_in[17];
  const float* genw = (const float*)d_in[18];
  const float* genb = (const float*)d_in[19];
  float* out = (float*)d_out;

  char* ws = (char*)d_ws;
  size_t off = 0;
  auto alloc = [&](size_t bytes)->char* {
    char* p = ws + off; off = (off + bytes + 255) & ~(size_t)255; return p;
  };
  _Float16* x_h    = (_Float16*)alloc((size_t)TSRC*NB*EMBP*2);
  _Float16* xrev_h = (_Float16*)alloc((size_t)TSRC*NB*EMBP*2);
  _Float16* pe_h   = (_Float16*)alloc((size_t)TDEC*NB*EMBP*2);
  _Float16* wihF_h = (_Float16*)alloc((size_t)2048*EMBP*2);
  _Float16* wihR_h = (_Float16*)alloc((size_t)2048*EMBP*2);
  _Float16* whhF_h = (_Float16*)alloc((size_t)2048*EH*2);
  _Float16* whhR_h = (_Float16*)alloc((size_t)2048*EH*2);
  _Float16* wm1_h  = (_Float16*)alloc((size_t)5120*DH*2);
  _Float16* wo_h   = (_Float16*)alloc((size_t)DH*2048*2);
  _Float16* w3c    = (_Float16*)alloc((size_t)4096*DH*2);
  _Float16* w3pe   = (_Float16*)alloc((size_t)4096*EMBP*2);
  _Float16* genw_h = (_Float16*)alloc((size_t)GVP*DH*2);
  float* b4f   = (float*)alloc(2048*4);
  float* b4r   = (float*)alloc(2048*4);
  float* db4   = (float*)alloc(4096*4);
  float* xp_f  = (float*)alloc((size_t)TSRC*NB*2048*4);
  float* xp_r  = (float*)alloc((size_t)TSRC*NB*2048*4);
  float* peproj = (float*)alloc((size_t)TDEC*NB*4096*4);
  _Float16* enc_out = (_Float16*)alloc((size_t)TSRC*NB*DH*2);
  _Float16* hbuf = (_Float16*)alloc((size_t)4*NB*EH*2);
  _Float16* dh = (_Float16*)alloc((size_t)NB*DH*2);
  float* dc = (float*)alloc((size_t)NB*DH*4);
  float* qb = (float*)alloc((size_t)NB*DH*4);
  float* gh = (float*)alloc((size_t)NB*4096*4);
  _Float16* st = (_Float16*)alloc((size_t)NB*DH*2);
  _Float16* ct = (_Float16*)alloc((size_t)NB*DH*2);
  _Float16* hdec = (_Float16*)alloc((size_t)3200*DH*2);
  int* flags = (int*)alloc(65536);
  (void)in_sizes; (void)n_in; (void)out_size; (void)ws_size;

  // --- init / zero state ---
  hipMemsetAsync(hbuf, 0, (size_t)4*NB*EH*2, stream);
  hipMemsetAsync(hdec + (size_t)3136*DH, 0, (size_t)64*DH*2, stream);
  hipMemsetAsync(genw_h + (size_t)GV*DH, 0, (size_t)(GVP-GV)*DH*2, stream);
  hipMemsetAsync(out, 0, (size_t)NB*GV*4, stream);
  hipMemsetAsync(flags, 0, 65536, stream);

  auto cgrid = [](size_t n){ return dim3((unsigned)((n + 255)/256)); };

  // --- weight conversion (fp16) ---
  cvt16s<<<cgrid((size_t)2048*EMBP),256,0,stream>>>(WihF, wihF_h, 2048, EMBD, EMBD, EMBP);
  cvt16s<<<cgrid((size_t)2048*EMBP),256,0,stream>>>(WihR, wihR_h, 2048, EMBD, EMBD, EMBP);
  cvt16s<<<cgrid((size_t)2048*EH),256,0,stream>>>(WhhF, whhF_h, 2048, EH, EH, EH);
  cvt16s<<<cgrid((size_t)2048*EH),256,0,stream>>>(WhhR, whhR_h, 2048, EH, EH, EH);
  cvt16s<<<cgrid((size_t)1024*DH),256,0,stream>>>(wi, wm1_h, 1024, DH, DH, DH);
  cvt16s<<<cgrid((size_t)4096*DH),256,0,stream>>>(dWhh, wm1_h + (size_t)1024*DH, 4096, DH, DH, DH);
  cvt16s<<<cgrid((size_t)DH*2048),256,0,stream>>>(wo, wo_h, DH, 2048, 2048, 2048);
  cvt16s<<<cgrid((size_t)4096*DH),256,0,stream>>>(dWih, w3c, 4096, 1324, 1024, 1024);
  cvt16s<<<cgrid((size_t)4096*EMBP),256,0,stream>>>(dWih + 1024, w3pe, 4096, 1324, 300, EMBP);
  cvt16s<<<cgrid((size_t)GV*DH),256,0,stream>>>(genw, genw_h, GV, DH, DH, DH);
  addb<<<cgrid(2048),256,0,stream>>>(bihF, bhhF, b4f, 2048);
  addb<<<cgrid(2048),256,0,stream>>>(bihR, bhhR, b4r, 2048);
  addb<<<cgrid(4096),256,0,stream>>>(dbih, dbhh, db4, 4096);
  k_embed<<<cgrid((size_t)(TSRC+TDEC)*NB*EMBP),256,0,stream>>>(src, trg, eemb, demb, x_h, xrev_h, pe_h);

  // --- projections ---
  gemm128<<<dim3(16,25),256,0,stream>>>(x_h,    EMBP, wihF_h, EMBP, b4f, xp_f, 2048, EMBP, 3200, 2048, 0);
  gemm128<<<dim3(16,25),256,0,stream>>>(xrev_h, EMBP, wihR_h, EMBP, b4r, xp_r, 2048, EMBP, 3200, 2048, 0);
  gemm128<<<dim3(32,25),256,0,stream>>>(pe_h, EMBP, w3pe, EMBP, db4, peproj, 4096, EMBP, 3136, 4096, 0);

  // --- persistent sequential kernel ---
  SA sa;
  sa.whhF = whhF_h; sa.whhR = whhR_h;
  sa.wm1 = wm1_h;
  sa.wo = wo_h;
  sa.w3c = w3c;
  sa.xpF = xp_f; sa.xpR = xp_r;
  sa.pp = peproj;
  sa.h = hbuf;
  sa.enc_out = enc_out;
  sa.dh = dh; sa.dc = dc;
  sa.q = qb; sa.gh = gh;
  sa.st = st; sa.ct = ct;
  sa.hdec = hdec;
  sa.flags = flags;
  hipFuncSetAttribute((const void*)seq_kernel,
                      hipFuncAttributeMaxDynamicSharedMemorySize, LDS_TOT);
  seq_kernel<<<dim3(GRIDN), 256, LDS_TOT, stream>>>(sa);

  // --- generator + log-softmax ---
  gemm128<<<dim3(GVP/128,25),256,0,stream>>>(hdec, DH, genw_h, DH, genb, out, GV, DH, 3136, GV, NB);
  lsm<<<3136,256,0,stream>>>(out);
}

// Round 10
// 2966.977 us; speedup vs baseline: 1.2203x; 1.2203x over previous
//
#include <hip/hip_runtime.h>
#include <cstdint>
#include <cmath>

// ---------------- dims ----------------
#define NB    64
#define EMBD  300
#define EMBP  320
#define EH    512
#define DH    1024
#define GV    23262
#define GVP   23296
#define TSRC  50
#define TDEC  49
#define LDS_SCR 131072
#define LDS_TOT (131072 + 16384 + 256)
#define LDS_ENC (65536 + 16384 + 256)
#define FS    32      // ints between flags (128 B)

typedef __attribute__((ext_vector_type(8))) _Float16 f16x8;
typedef __attribute__((ext_vector_type(4))) float f32x4;

__device__ __forceinline__ float sigm(float x){ return 1.f/(1.f+expf(-x)); }

// ---- write-through (agent-scope relaxed atomic) stores, packed ----
__device__ __forceinline__ void cohS16(_Float16* p, _Float16 v){
  union { _Float16 f; unsigned short u; } c; c.f = v;
  __hip_atomic_store((unsigned short*)p, c.u, __ATOMIC_RELAXED, __HIP_MEMORY_SCOPE_AGENT);
}
__device__ __forceinline__ void cohS32(float* p, float v){
  __hip_atomic_store(p, v, __ATOMIC_RELAXED, __HIP_MEMORY_SCOPE_AGENT);
}
__device__ __forceinline__ void cohS64(void* p, unsigned long long v){
  __hip_atomic_store((unsigned long long*)p, v, __ATOMIC_RELAXED, __HIP_MEMORY_SCOPE_AGENT);
}
__device__ __forceinline__ void cohS32u(void* p, unsigned int v){
  __hip_atomic_store((unsigned int*)p, v, __ATOMIC_RELAXED, __HIP_MEMORY_SCOPE_AGENT);
}
__device__ __forceinline__ unsigned short h2u(float f){
  union { _Float16 h; unsigned short u; } c; c.h = (_Float16)f; return c.u;
}
__device__ __forceinline__ unsigned long long pk4h(float a, float b, float c, float d){
  return (unsigned long long)h2u(a) | ((unsigned long long)h2u(b)<<16)
       | ((unsigned long long)h2u(c)<<32) | ((unsigned long long)h2u(d)<<48);
}
__device__ __forceinline__ unsigned int pk2h(float a, float b){
  return (unsigned int)h2u(a) | ((unsigned int)h2u(b)<<16);
}

// ---- flags: producers post own flag (no RMW); consumers poll in parallel,
// then one acquire fence per WG (inv L1/L2 -> cached loads see fresh data,
// XCD L2 amortizes refetch across its WGs).
__device__ __forceinline__ int ldF(int* p){
  return __hip_atomic_load(p, __ATOMIC_RELAXED, __HIP_MEMORY_SCOPE_AGENT);
}
__device__ __forceinline__ void stF(int* p, int v){
  __hip_atomic_store(p, v, __ATOMIC_RELAXED, __HIP_MEMORY_SCOPE_AGENT);
}
__device__ __forceinline__ void post(int* flagArr, int idx, int epoch){
  __syncthreads();   // drain this WG's write-through stores
  if (threadIdx.x == 0) stF(flagArr + idx*FS, epoch);
}
__device__ __forceinline__ void flagWaitIdx(int* flagArr, int myIdx, bool active, int epoch)
{
  if (active) {
    int* p = flagArr + myIdx*FS;
    while (ldF(p) < epoch) __builtin_amdgcn_s_sleep(2);
  }
  __syncthreads();
  if (threadIdx.x == 0) __builtin_amdgcn_fence(__ATOMIC_ACQUIRE, "agent");
  __syncthreads();
}

// ---- stage a [nrows][ncols] fp16 tile into LDS with XOR-16B swizzle ----
__device__ __forceinline__ void stageW(char* dst, const _Float16* __restrict__ src,
                                       int srcld, int nrows, int ncols, int tid)
{
  const int nch = ncols >> 3;
  for (int i = tid; i < nrows*nch; i += 256) {
    int row = i / nch, c = i - row*nch;
    *(f16x8*)(dst + row*ncols*2 + ((c*16) ^ ((row&7)<<4))) =
        *(const f16x8*)(src + (size_t)row*srcld + c*8);
  }
}

// 64x16 MFMA tile: acc += A[64][K](plain cached) @ B[16][K](LDS swizzled)^T
template<int K>
__device__ __forceinline__ void mm16L(f32x4 (&acc)[4],
    const _Float16* __restrict__ A, int lda,
    const char* ldsB, int rowbytes, int koffB, int lane)
{
  const int r = lane & 15, q = lane >> 4;
  const _Float16* a0 = A + r*lda + q*8;
  const char* b0 = ldsB + r*rowbytes + koffB;
  const int sw = (r & 7) << 4;
#pragma unroll
  for (int g = 0; g < K/256; ++g) {
    f16x8 av[8][4], bv[8];
#pragma unroll
    for (int s = 0; s < 8; ++s) {
      int sl = g*8 + s;
      bv[s] = *(const f16x8*)(b0 + ((sl*64 + q*16) ^ sw));
#pragma unroll
      for (int m = 0; m < 4; ++m)
        av[s][m] = *(const f16x8*)(a0 + m*16*lda + sl*32);
    }
#pragma unroll
    for (int s = 0; s < 8; ++s)
#pragma unroll
      for (int m = 0; m < 4; ++m)
        acc[m] = __builtin_amdgcn_mfma_f32_16x16x32_f16(av[s][m], bv[s], acc[m], 0, 0, 0);
  }
}

// ---------------- prep kernels ----------------
__global__ void cvt16s(const float* __restrict__ src, _Float16* __restrict__ dst,
                       int rows, int sld, int scols, int dcols)
{
  int idx = blockIdx.x*256 + threadIdx.x;
  if (idx >= rows*dcols) return;
  int c = idx % dcols, rr = idx / dcols;
  dst[idx] = (c < scols) ? (_Float16)src[(size_t)rr*sld + c] : (_Float16)0.f;
}

// n x n fp32 -> fp16 transpose (for wi^T used by the eq GEMM)
__global__ void cvt16t(const float* __restrict__ src, _Float16* __restrict__ dst, int n)
{
  int idx = blockIdx.x*256 + threadIdx.x;
  if (idx >= n*n) return;
  int rr = idx / n, c = idx - rr*n;
  dst[(size_t)c*n + rr] = (_Float16)src[idx];
}

__global__ void addb(const float* __restrict__ a, const float* __restrict__ b,
                     float* __restrict__ o, int n)
{
  int i = blockIdx.x*256 + threadIdx.x;
  if (i < n) o[i] = a[i] + b[i];
}

__global__ void k_embed(const int* __restrict__ src, const int* __restrict__ trg,
                        const float* __restrict__ eemb, const float* __restrict__ demb,
                        _Float16* __restrict__ x_h, _Float16* __restrict__ xrev_h,
                        _Float16* __restrict__ pe_h)
{
  int idx = blockIdx.x*256 + threadIdx.x;
  const int tot1 = TSRC*NB*EMBP;
  const int tot2 = TDEC*NB*EMBP;
  if (idx < tot1) {
    int e = idx % EMBP, rb = idx / EMBP;
    int t = rb >> 6, b = rb & 63;
    float v = 0.f;
    if (e < EMBD) v = eemb[(size_t)src[rb]*EMBD + e];
    _Float16 hv = (_Float16)v;
    x_h[idx] = hv;
    xrev_h[(size_t)((TSRC-1-t)*NB + b)*EMBP + e] = hv;
  } else if (idx < tot1 + tot2) {
    int k = idx - tot1;
    int e = k % EMBP, rb = k / EMBP;
    float v = 0.f;
    if (e < EMBD) v = demb[(size_t)trg[rb]*EMBD + e];
    pe_h[k] = (_Float16)v;
  }
}

// ---------------- big tiled GEMM (throughput path), fp16 in / f32 out ----------------
__global__ __launch_bounds__(256) void gemm128(
    const _Float16* __restrict__ A, int lda,
    const _Float16* __restrict__ W, int ldw,
    const float* __restrict__ bias,
    float* __restrict__ out, int ldo,
    int K, int mvalid, int nvalid, int rowoff)
{
  __shared__ _Float16 As[128*64];
  __shared__ _Float16 Bs[128*64];
  const int tid = threadIdx.x;
  const int m0 = blockIdx.y*128, n0 = blockIdx.x*128;
  const int w = tid >> 6, lane = tid & 63, r = lane & 15, q = lane >> 4;
  const int mw = (w >> 1)*64, nw = (w & 1)*64;
  f32x4 acc[4][4];
#pragma unroll
  for (int mi=0; mi<4; ++mi)
#pragma unroll
    for (int ni=0; ni<4; ++ni) acc[mi][ni] = 0.f;

  for (int kt = 0; kt < K; kt += 64) {
    f16x8 ra[4], rb[4];
#pragma unroll
    for (int j = 0; j < 4; ++j) {
      int c = j*256 + tid, row = c >> 3, cc = c & 7;
      ra[j] = *(const f16x8*)(A + (size_t)(m0+row)*lda + kt + cc*8);
      rb[j] = *(const f16x8*)(W + (size_t)(n0+row)*ldw + kt + cc*8);
    }
    __syncthreads();
#pragma unroll
    for (int j = 0; j < 4; ++j) {
      int c = j*256 + tid, row = c >> 3, cc = c & 7;
      int sw = cc ^ (row & 7);
      *(f16x8*)((char*)As + row*128 + (sw<<4)) = ra[j];
      *(f16x8*)((char*)Bs + row*128 + (sw<<4)) = rb[j];
    }
    __syncthreads();
#pragma unroll
    for (int kk = 0; kk < 64; kk += 32) {
      int ch = (kk >> 3) + q;
      f16x8 av[4], bv[4];
#pragma unroll
      for (int mi=0; mi<4; ++mi) {
        int row = mw + mi*16 + r;
        av[mi] = *(const f16x8*)((char*)As + row*128 + ((ch ^ (row&7))<<4));
      }
#pragma unroll
      for (int ni=0; ni<4; ++ni) {
        int row = nw + ni*16 + r;
        bv[ni] = *(const f16x8*)((char*)Bs + row*128 + ((ch ^ (row&7))<<4));
      }
#pragma unroll
      for (int mi=0; mi<4; ++mi)
#pragma unroll
        for (int ni=0; ni<4; ++ni)
          acc[mi][ni] = __builtin_amdgcn_mfma_f32_16x16x32_f16(av[mi], bv[ni], acc[mi][ni], 0,0,0);
    }
  }
#pragma unroll
  for (int mi=0; mi<4; ++mi)
#pragma unroll
    for (int ni=0; ni<4; ++ni)
#pragma unroll
      for (int e=0; e<4; ++e) {
        int mrow = m0 + mw + mi*16 + q*4 + e;
        int col  = n0 + nw + ni*16 + r;
        if (mrow < mvalid && col < nvalid)
          out[(size_t)(mrow + rowoff)*ldo + col] = acc[mi][ni][e] + bias[col];
      }
}

// same GEMM but fp16 output (for eq)
__global__ __launch_bounds__(256) void gemm128h(
    const _Float16* __restrict__ A, int lda,
    const _Float16* __restrict__ W, int ldw,
    const float* __restrict__ bias,
    _Float16* __restrict__ out, int ldo,
    int K, int mvalid, int nvalid)
{
  __shared__ _Float16 As[128*64];
  __shared__ _Float16 Bs[128*64];
  const int tid = threadIdx.x;
  const int m0 = blockIdx.y*128, n0 = blockIdx.x*128;
  const int w = tid >> 6, lane = tid & 63, r = lane & 15, q = lane >> 4;
  const int mw = (w >> 1)*64, nw = (w & 1)*64;
  f32x4 acc[4][4];
#pragma unroll
  for (int mi=0; mi<4; ++mi)
#pragma unroll
    for (int ni=0; ni<4; ++ni) acc[mi][ni] = 0.f;

  for (int kt = 0; kt < K; kt += 64) {
    f16x8 ra[4], rb[4];
#pragma unroll
    for (int j = 0; j < 4; ++j) {
      int c = j*256 + tid, row = c >> 3, cc = c & 7;
      ra[j] = *(const f16x8*)(A + (size_t)(m0+row)*lda + kt + cc*8);
      rb[j] = *(const f16x8*)(W + (size_t)(n0+row)*ldw + kt + cc*8);
    }
    __syncthreads();
#pragma unroll
    for (int j = 0; j < 4; ++j) {
      int c = j*256 + tid, row = c >> 3, cc = c & 7;
      int sw = cc ^ (row & 7);
      *(f16x8*)((char*)As + row*128 + (sw<<4)) = ra[j];
      *(f16x8*)((char*)Bs + row*128 + (sw<<4)) = rb[j];
    }
    __syncthreads();
#pragma unroll
    for (int kk = 0; kk < 64; kk += 32) {
      int ch = (kk >> 3) + q;
      f16x8 av[4], bv[4];
#pragma unroll
      for (int mi=0; mi<4; ++mi) {
        int row = mw + mi*16 + r;
        av[mi] = *(const f16x8*)((char*)As + row*128 + ((ch ^ (row&7))<<4));
      }
#pragma unroll
      for (int ni=0; ni<4; ++ni) {
        int row = nw + ni*16 + r;
        bv[ni] = *(const f16x8*)((char*)Bs + row*128 + ((ch ^ (row&7))<<4));
      }
#pragma unroll
      for (int mi=0; mi<4; ++mi)
#pragma unroll
        for (int ni=0; ni<4; ++ni)
          acc[mi][ni] = __builtin_amdgcn_mfma_f32_16x16x32_f16(av[mi], bv[ni], acc[mi][ni], 0,0,0);
    }
  }
#pragma unroll
  for (int mi=0; mi<4; ++mi)
#pragma unroll
    for (int ni=0; ni<4; ++ni)
#pragma unroll
      for (int e=0; e<4; ++e) {
        int mrow = m0 + mw + mi*16 + q*4 + e;
        int col  = n0 + nw + ni*16 + r;
        if (mrow < mvalid && col < nvalid)
          out[(size_t)mrow*ldo + col] = (_Float16)(acc[mi][ni][e] + bias[col]);
      }
}

// ---------------- persistent encoder (64 WGs, 1 hop/step) ----------------
struct EA {
  const _Float16 *whhF, *whhR;   // [2048][512]
  const float *xpF, *xpR;        // [50*64][2048] (bias folded)
  _Float16 *h;                   // [2 dir][2 buf][64][512]
  _Float16 *enc_out;             // [50][64][1024]
  _Float16 *dh;                  // [64][1024]
  float *dc;                     // [64][1024]
  int *flags;                    // 64
};

__global__ __launch_bounds__(256, 1) void enc_seq(EA a)
{
  extern __shared__ char lds[];
  const int tid = threadIdx.x, w = tid >> 6, lane = tid & 63;
  const int wgid = blockIdx.x;
  const int r = lane & 15, q4 = lane >> 4;
  float (*sm4)[64][16] = (float(*)[64][16])(lds + 65536);

  const int dir = wgid >> 5, j0 = (wgid & 31) << 4;
  const _Float16* whh = dir ? a.whhR : a.whhF;
  for (int g = 0; g < 4; ++g)
    stageW(lds + g*16384, whh + (size_t)(g*EH + j0)*EH, EH, 16, 512, tid);
  __syncthreads();

  const int b = tid >> 2, jq = (tid & 3) * 4;
  float creg[4] = {0.f, 0.f, 0.f, 0.f};
  const float* xpbase = dir ? a.xpR : a.xpF;

  for (int t = 0; t < TSRC; ++t) {
    float xr[4][4];
#pragma unroll
    for (int g = 0; g < 4; ++g)
#pragma unroll
      for (int k = 0; k < 4; ++k)
        xr[g][k] = xpbase[((size_t)t*NB + b)*2048 + g*EH + j0 + jq + k];
    if (t) flagWaitIdx(a.flags, dir*32 + tid, tid < 32, t);
    const int cur = t & 1;
    const _Float16* H = a.h + (size_t)(dir*2 + cur)*NB*EH;
    f32x4 acc[4];
#pragma unroll
    for (int m=0;m<4;++m) acc[m] = 0.f;
    mm16L<EH>(acc, H, EH, lds + w*16384, 1024, 0, lane);
#pragma unroll
    for (int m=0;m<4;++m)
#pragma unroll
      for (int e=0;e<4;++e) sm4[w][m*16 + q4*4 + e][r] = acc[m][e];
    __syncthreads();
    _Float16* Ho = a.h + (size_t)(dir*2 + (cur^1))*NB*EH;
    const int erow = dir ? (TSRC-1 - t) : t;
    float hv[4];
#pragma unroll
    for (int k = 0; k < 4; ++k) {
      int jj = jq + k;
      float gi = sm4[0][b][jj] + xr[0][k];
      float gf = sm4[1][b][jj] + xr[1][k];
      float gg = sm4[2][b][jj] + xr[2][k];
      float go = sm4[3][b][jj] + xr[3][k];
      float cn = sigm(gf)*creg[k] + sigm(gi)*tanhf(gg);
      creg[k] = cn;
      hv[k] = sigm(go)*tanhf(cn);
    }
    cohS64(Ho + b*EH + j0 + jq, pk4h(hv[0],hv[1],hv[2],hv[3]));
    cohS64(a.enc_out + ((size_t)erow*NB + b)*DH + dir*EH + j0 + jq, pk4h(hv[0],hv[1],hv[2],hv[3]));
    if (t == TSRC-1) {
#pragma unroll
      for (int k = 0; k < 4; ++k) {
        int j = j0 + jq + k;
        cohS16(a.dh + b*DH + 2*j + dir, (_Float16)hv[k]);
        cohS32(a.dc + b*DH + 2*j + dir, creg[k]);
      }
    }
    post(a.flags, wgid, t+1);
  }
}

// ---------------- persistent decoder (224 WGs, 3 hops/step) ----------------
// roles: 0-63 P2 (attention via precomputed eq) | 64-191 D (dWhh·dh + w3c·ct
// fused, LSTM) | 192-223 C (ct = tanh(wo·[st;dh]), dh-part pre-overlapped)
struct DA {
  const _Float16 *wo;            // [1024][2048]
  const _Float16 *wdh;           // [4096][1024] dec_Whh
  const _Float16 *w3c;           // [4096][1024] dWih ct-part
  const _Float16 *eq;            // [3200][1024] enc_out @ wi (fp16)
  const _Float16 *enc_out;       // [50][64][1024]
  const float *pp;               // [49*64][4096] pe-proj + biases
  _Float16 *dh;                  // [64][1024]
  float *dc;                     // [64][1024] (enc handoff)
  _Float16 *st, *ct;             // [64][1024]
  _Float16 *hdec;                // [3200][1024]
  int *flags;                    // FB 64 | FC 32 | FD 128
};

__global__ __launch_bounds__(256, 1) void dec_seq(DA a)
{
  extern __shared__ char lds[];
  const int tid = threadIdx.x, w = tid >> 6, lane = tid & 63;
  const int wgid = blockIdx.x;
  const int r = lane & 15, q4 = lane >> 4;
  float (*sm4)[64][16] = (float(*)[64][16])(lds + LDS_SCR);
  float* qs = (float*)(lds + LDS_SCR);           // P2 dh row (aliases sm4)
  float* sc = (float*)(lds + LDS_SCR + 16384);

  int* FB = a.flags;
  int* FC = FB + 64*FS;
  int* FD = FC + 32*FS;

  // ---- stage weights ----
  if (wgid >= 64 && wgid < 192) {
    int i = wgid - 64;
    for (int g = 0; g < 4; ++g)
      stageW(lds + g*8*2048, a.wdh + (size_t)(g*1024 + i*8)*DH, DH, 8, 1024, tid);
    for (int g = 0; g < 4; ++g)
      stageW(lds + 65536 + g*8*2048, a.w3c + (size_t)(g*1024 + i*8)*DH, DH, 8, 1024, tid);
  } else if (wgid >= 192) {
    int i = wgid - 192;
    stageW(lds,         a.wo + (size_t)i*32*2048,        2048, 32, 1024, tid);  // st-part
    stageW(lds + 65536, a.wo + (size_t)i*32*2048 + 1024, 2048, 32, 1024, tid);  // dh-part
  }
  __syncthreads();

  const bool isP2 = (wgid < 64);
  const bool isD  = (wgid >= 64 && wgid < 192);
  const bool isC  = (wgid >= 192);

  float dcreg[2] = {0.f, 0.f};

  for (int t = 0; t < TDEC; ++t) {
    // ---- P2: scores = eq·dh, softmax, st (one batch element per WG) ----
    if (isP2) {
      if (t) flagWaitIdx(FD, tid, tid < 128, t);
      const int b = wgid;
      if (tid < 128) {
        f16x8 v = *(const f16x8*)(a.dh + b*DH + tid*8);
#pragma unroll
        for (int k = 0; k < 8; ++k) qs[tid*8 + k] = (float)v[k];
      }
      __syncthreads();
      for (int tt = w; tt < TSRC; tt += 4) {
        const _Float16* er = a.eq + ((size_t)tt*NB + b)*DH + lane*16;
        const float* qq = qs + lane*16;
        f16x8 e0 = *(const f16x8*)(er);
        f16x8 e1 = *(const f16x8*)(er + 8);
        float s = 0.f;
#pragma unroll
        for (int ii=0; ii<8; ++ii) s += (float)e0[ii]*qq[ii];
#pragma unroll
        for (int ii=0; ii<8; ++ii) s += (float)e1[ii]*qq[8+ii];
#pragma unroll
        for (int o=32; o; o>>=1) s += __shfl_xor(s, o);
        if (lane == 0) sc[tt] = s;
      }
      __syncthreads();
      float mx = -1e30f;
      for (int tt=0; tt<TSRC; ++tt) mx = fmaxf(mx, sc[tt]);
      __syncthreads();
      if (tid < TSRC) sc[tid] = expf(sc[tid] - mx);
      __syncthreads();
      float s50 = 0.f;
      for (int tt=0; tt<TSRC; ++tt) s50 += sc[tt];
      const float inv = 1.f/s50;
      const int c0 = tid*4;
      float a0=0.f, a1=0.f, a2=0.f, a3=0.f;
      for (int tt=0; tt<TSRC; ++tt) {
        float wt = sc[tt];
        const _Float16* er = a.enc_out + ((size_t)tt*NB + b)*DH + c0;
        a0 += wt*(float)er[0]; a1 += wt*(float)er[1];
        a2 += wt*(float)er[2]; a3 += wt*(float)er[3];
      }
      cohS64(a.st + b*DH + c0, pk4h(a0*inv, a1*inv, a2*inv, a3*inv));
      post(FB, wgid, t+1);
    }

    // ---- C: ct = tanh(wo_st·st + wo_dh·dh); dh-part overlapped with P2 ----
    if (isC) {
      if (t) flagWaitIdx(FD, tid, tid < 128, t);
      const int i = wgid - 192, col0 = i*32;
      const int cs = w >> 1, kh = w & 1;
      f32x4 acc[4];
#pragma unroll
      for (int m=0;m<4;++m) acc[m] = 0.f;
      mm16L<512>(acc, a.dh + kh*512, DH, lds + 65536 + cs*16*2048, 2048, kh*1024, lane);
      flagWaitIdx(FB, tid, tid < 64, t+1);
      mm16L<512>(acc, a.st + kh*512, DH, lds + cs*16*2048, 2048, kh*1024, lane);
#pragma unroll
      for (int m=0;m<4;++m)
#pragma unroll
        for (int e=0;e<4;++e) sm4[w][m*16 + q4*4 + e][r] = acc[m][e];
      __syncthreads();
      const int b = tid >> 2, cc0 = (tid & 3)*8;
      float v[8];
#pragma unroll
      for (int k = 0; k < 8; ++k) {
        int cc = cc0 + k;
        v[k] = tanhf(sm4[(cc>>4)*2][b][cc&15] + sm4[(cc>>4)*2+1][b][cc&15]);
      }
      cohS64(a.ct + b*DH + col0 + cc0,     pk4h(v[0],v[1],v[2],v[3]));
      cohS64(a.ct + b*DH + col0 + cc0 + 4, pk4h(v[4],v[5],v[6],v[7]));
      post(FC, i, t+1);
    }

    // ---- D: gates = dWhh·dh (after FD) + w3c·ct (after FC) + pp; LSTM ----
    if (isD) {
      const int i = wgid - 64;
      if (t) flagWaitIdx(FD, tid, tid < 128, t);
      const int b = tid >> 2, j0 = i*8, jj2 = (tid & 3)*2;
      if (t == 0) {
        dcreg[0] = a.dc[b*DH + j0 + jj2];
        dcreg[1] = a.dc[b*DH + j0 + jj2 + 1];
      }
      const int cs = w >> 1, kh = w & 1;
      f32x4 acc[4];
#pragma unroll
      for (int m=0;m<4;++m) acc[m] = 0.f;
      mm16L<512>(acc, a.dh + kh*512, DH, lds + cs*16*2048, 2048, kh*1024, lane);
      // prefetch pp (read-only) before the FC fence; values live in registers
      float ppv[4][2];
#pragma unroll
      for (int g = 0; g < 4; ++g)
#pragma unroll
        for (int k = 0; k < 2; ++k)
          ppv[g][k] = a.pp[((size_t)t*NB + b)*4096 + g*DH + j0 + jj2 + k];
      flagWaitIdx(FC, tid, tid < 32, t+1);
      mm16L<512>(acc, a.ct + kh*512, DH, lds + 65536 + cs*16*2048, 2048, kh*1024, lane);
#pragma unroll
      for (int m=0;m<4;++m)
#pragma unroll
        for (int e=0;e<4;++e) sm4[w][m*16 + q4*4 + e][r] = acc[m][e];
      __syncthreads();
      float hv[2];
#pragma unroll
      for (int k = 0; k < 2; ++k) {
        int jj = jj2 + k;
        float gi = sm4[0][b][jj]   + sm4[1][b][jj]   + ppv[0][k];
        float gf = sm4[0][b][8+jj] + sm4[1][b][8+jj] + ppv[1][k];
        float gg = sm4[2][b][jj]   + sm4[3][b][jj]   + ppv[2][k];
        float go = sm4[2][b][8+jj] + sm4[3][b][8+jj] + ppv[3][k];
        float cn = sigm(gf)*dcreg[k] + sigm(gi)*tanhf(gg);
        dcreg[k] = cn;
        hv[k] = sigm(go)*tanhf(cn);
      }
      cohS32u(a.dh + b*DH + j0 + jj2, pk2h(hv[0], hv[1]));
      cohS32u(a.hdec + ((size_t)t*NB + b)*DH + j0 + jj2, pk2h(hv[0], hv[1]));
      post(FD, i, t+1);
    }
  }
}

// ---------------- in-place log-softmax over vocab rows ----------------
__global__ __launch_bounds__(256) void lsm(float* __restrict__ out)
{
  const int row = NB + blockIdx.x;
  float* p = out + (size_t)row*GV;
  const int tid = threadIdx.x;
  __shared__ float red[4], red2[4];
  float mx = -1e30f;
  for (int i = tid; i < GV; i += 256) mx = fmaxf(mx, p[i]);
  for (int off=32; off; off>>=1) mx = fmaxf(mx, __shfl_down(mx, off));
  if ((tid & 63) == 0) red[tid>>6] = mx;
  __syncthreads();
  mx = fmaxf(fmaxf(red[0],red[1]), fmaxf(red[2],red[3]));
  float sm = 0.f;
  for (int i = tid; i < GV; i += 256) sm += expf(p[i] - mx);
  for (int off=32; off; off>>=1) sm += __shfl_down(sm, off);
  if ((tid & 63) == 0) red2[tid>>6] = sm;
  __syncthreads();
  sm = red2[0]+red2[1]+red2[2]+red2[3];
  float lse = mx + logf(sm);
  for (int i = tid; i < GV; i += 256) p[i] -= lse;
}

// ---------------- host ----------------
extern "C" void kernel_launch(void* const* d_in, const int* in_sizes, int n_in,
                              void* d_out, int out_size, void* d_ws, size_t ws_size,
                              hipStream_t stream)
{
  const int*   src  = (const int*)d_in[0];
  const int*   trg  = (const int*)d_in[1];
  const float* WihF = (const float*)d_in[2];
  const float* WhhF = (const float*)d_in[3];
  const float* bihF = (const float*)d_in[4];
  const float* bhhF = (const float*)d_in[5];
  const float* WihR = (const float*)d_in[6];
  const float* WhhR = (const float*)d_in[7];
  const float* bihR = (const float*)d_in[8];
  const float* bhhR = (const float*)d_in[9];
  const float* dWih = (const float*)d_in[10];
  const float* dWhh = (const float*)d_in[11];
  const float* dbih = (const float*)d_in[12];
  const float* dbhh = (const float*)d_in[13];
  const float* eemb = (const float*)d_in[14];
  const float* demb = (const float*)d_in[15];
  const float* wi   = (const float*)d_in[16];
  const float* wo   = (const float*)d_in[17];
  const float* genw = (const float*)d_in[18];
  const float* genb = (const float*)d_in[19];
  float* out = (float*)d_out;

  char* ws = (char*)d_ws;
  size_t off = 0;
  auto alloc = [&](size_t bytes)->char* {
    char* p = ws + off; off = (off + bytes + 255) & ~(size_t)255; return p;
  };
  _Float16* x_h    = (_Float16*)alloc((size_t)TSRC*NB*EMBP*2);
  _Float16* xrev_h = (_Float16*)alloc((size_t)TSRC*NB*EMBP*2);
  _Float16* pe_h   = (_Float16*)alloc((size_t)TDEC*NB*EMBP*2);
  _Float16* wihF_h = (_Float16*)alloc((size_t)2048*EMBP*2);
  _Float16* wihR_h = (_Float16*)alloc((size_t)2048*EMBP*2);
  _Float16* whhF_h = (_Float16*)alloc((size_t)2048*EH*2);
  _Float16* whhR_h = (_Float16*)alloc((size_t)2048*EH*2);
  _Float16* wdh_h  = (_Float16*)alloc((size_t)4096*DH*2);
  _Float16* wo_h   = (_Float16*)alloc((size_t)DH*2048*2);
  _Float16* w3c    = (_Float16*)alloc((size_t)4096*DH*2);
  _Float16* w3pe   = (_Float16*)alloc((size_t)4096*EMBP*2);
  _Float16* wiT_h  = (_Float16*)alloc((size_t)DH*DH*2);
  _Float16* genw_h = (_Float16*)alloc((size_t)GVP*DH*2);
  float* b4f   = (float*)alloc(2048*4);
  float* b4r   = (float*)alloc(2048*4);
  float* db4   = (float*)alloc(4096*4);
  float* zb    = (float*)alloc(DH*4);
  float* xp_f  = (float*)alloc((size_t)TSRC*NB*2048*4);
  float* xp_r  = (float*)alloc((size_t)TSRC*NB*2048*4);
  float* peproj = (float*)alloc((size_t)TDEC*NB*4096*4);
  _Float16* enc_out = (_Float16*)alloc((size_t)TSRC*NB*DH*2);
  _Float16* eq_h = (_Float16*)alloc((size_t)TSRC*NB*DH*2);
  _Float16* hbuf = (_Float16*)alloc((size_t)4*NB*EH*2);
  _Float16* dh = (_Float16*)alloc((size_t)NB*DH*2);
  float* dc = (float*)alloc((size_t)NB*DH*4);
  _Float16* st = (_Float16*)alloc((size_t)NB*DH*2);
  _Float16* ct = (_Float16*)alloc((size_t)NB*DH*2);
  _Float16* hdec = (_Float16*)alloc((size_t)3200*DH*2);
  int* eflags = (int*)alloc(64*FS*4);
  int* dflags = (int*)alloc(224*FS*4);
  (void)in_sizes; (void)n_in; (void)out_size; (void)ws_size;

  // --- init / zero state (graph replays don't re-poison) ---
  hipMemsetAsync(hbuf, 0, (size_t)4*NB*EH*2, stream);
  hipMemsetAsync(hdec + (size_t)3136*DH, 0, (size_t)64*DH*2, stream);
  hipMemsetAsync(genw_h + (size_t)GV*DH, 0, (size_t)(GVP-GV)*DH*2, stream);
  hipMemsetAsync(out, 0, (size_t)NB*GV*4, stream);
  hipMemsetAsync(zb, 0, DH*4, stream);
  hipMemsetAsync(eflags, 0, 64*FS*4, stream);
  hipMemsetAsync(dflags, 0, 224*FS*4, stream);

  auto cgrid = [](size_t n){ return dim3((unsigned)((n + 255)/256)); };

  // --- weight conversion (fp16) ---
  cvt16s<<<cgrid((size_t)2048*EMBP),256,0,stream>>>(WihF, wihF_h, 2048, EMBD, EMBD, EMBP);
  cvt16s<<<cgrid((size_t)2048*EMBP),256,0,stream>>>(WihR, wihR_h, 2048, EMBD, EMBD, EMBP);
  cvt16s<<<cgrid((size_t)2048*EH),256,0,stream>>>(WhhF, whhF_h, 2048, EH, EH, EH);
  cvt16s<<<cgrid((size_t)2048*EH),256,0,stream>>>(WhhR, whhR_h, 2048, EH, EH, EH);
  cvt16s<<<cgrid((size_t)4096*DH),256,0,stream>>>(dWhh, wdh_h, 4096, DH, DH, DH);
  cvt16s<<<cgrid((size_t)DH*2048),256,0,stream>>>(wo, wo_h, DH, 2048, 2048, 2048);
  cvt16s<<<cgrid((size_t)4096*DH),256,0,stream>>>(dWih, w3c, 4096, 1324, 1024, 1024);
  cvt16s<<<cgrid((size_t)4096*EMBP),256,0,stream>>>(dWih + 1024, w3pe, 4096, 1324, 300, EMBP);
  cvt16t<<<cgrid((size_t)DH*DH),256,0,stream>>>(wi, wiT_h, DH);
  cvt16s<<<cgrid((size_t)GV*DH),256,0,stream>>>(genw, genw_h, GV, DH, DH, DH);
  addb<<<cgrid(2048),256,0,stream>>>(bihF, bhhF, b4f, 2048);
  addb<<<cgrid(2048),256,0,stream>>>(bihR, bhhR, b4r, 2048);
  addb<<<cgrid(4096),256,0,stream>>>(dbih, dbhh, db4, 4096);
  k_embed<<<cgrid((size_t)(TSRC+TDEC)*NB*EMBP),256,0,stream>>>(src, trg, eemb, demb, x_h, xrev_h, pe_h);

  // --- input projections ---
  gemm128<<<dim3(16,25),256,0,stream>>>(x_h,    EMBP, wihF_h, EMBP, b4f, xp_f, 2048, EMBP, 3200, 2048, 0);
  gemm128<<<dim3(16,25),256,0,stream>>>(xrev_h, EMBP, wihR_h, EMBP, b4r, xp_r, 2048, EMBP, 3200, 2048, 0);
  gemm128<<<dim3(32,25),256,0,stream>>>(pe_h, EMBP, w3pe, EMBP, db4, peproj, 4096, EMBP, 3136, 4096, 0);

  // --- encoder (persistent, 64 WGs) ---
  EA ea;
  ea.whhF = whhF_h; ea.whhR = whhR_h;
  ea.xpF = xp_f; ea.xpR = xp_r;
  ea.h = hbuf; ea.enc_out = enc_out;
  ea.dh = dh; ea.dc = dc;
  ea.flags = eflags;
  hipFuncSetAttribute((const void*)enc_seq,
                      hipFuncAttributeMaxDynamicSharedMemorySize, LDS_ENC);
  enc_seq<<<dim3(64), 256, LDS_ENC, stream>>>(ea);

  // --- eq = enc_out @ wi  (kills the decoder's q phase/hop) ---
  gemm128h<<<dim3(8,25),256,0,stream>>>(enc_out, DH, wiT_h, DH, zb, eq_h, DH, DH, 3200, DH);

  // --- decoder (persistent, 224 WGs, 3 hops/step) ---
  DA da;
  da.wo = wo_h; da.wdh = wdh_h; da.w3c = w3c;
  da.eq = eq_h; da.enc_out = enc_out;
  da.pp = peproj;
  da.dh = dh; da.dc = dc;
  da.st = st; da.ct = ct;
  da.hdec = hdec;
  da.flags = dflags;
  hipFuncSetAttribute((const void*)dec_seq,
                      hipFuncAttributeMaxDynamicSharedMemorySize, LDS_TOT);
  dec_seq<<<dim3(224), 256, LDS_TOT, stream>>>(da);

  // --- generator + log-softmax ---
  gemm128<<<dim3(GVP/128,25),256,0,stream>>>(hdec, DH, genw_h, DH, genb, out, GV, DH, 3136, GV, NB);
  lsm<<<3136,256,0,stream>>>(out);
}

// Round 11
// 2619.232 us; speedup vs baseline: 1.3823x; 1.1328x over previous
//
#include <hip/hip_runtime.h>
#include <cstdint>
#include <cmath>

// ---------------- dims ----------------
#define NB    64
#define EMBD  300
#define EMBP  320
#define EH    512
#define DH    1024
#define GV    23262
#define GVP   23296
#define TSRC  50
#define TDEC  49
#define LDS_SCR 131072
#define LDS_TOT (131072 + 16384 + 256)
#define LDS_ENC (65536 + 16384 + 256)
#define FS    32      // ints between flags (128 B)

typedef __attribute__((ext_vector_type(8))) _Float16 f16x8;
typedef __attribute__((ext_vector_type(4))) float f32x4;

__device__ __forceinline__ float sigm(float x){ return 1.f/(1.f+expf(-x)); }

// ---- write-through (agent-scope relaxed atomic) stores, packed ----
__device__ __forceinline__ void cohS16(_Float16* p, _Float16 v){
  union { _Float16 f; unsigned short u; } c; c.f = v;
  __hip_atomic_store((unsigned short*)p, c.u, __ATOMIC_RELAXED, __HIP_MEMORY_SCOPE_AGENT);
}
__device__ __forceinline__ void cohS32(float* p, float v){
  __hip_atomic_store(p, v, __ATOMIC_RELAXED, __HIP_MEMORY_SCOPE_AGENT);
}
__device__ __forceinline__ void cohS64(void* p, unsigned long long v){
  __hip_atomic_store((unsigned long long*)p, v, __ATOMIC_RELAXED, __HIP_MEMORY_SCOPE_AGENT);
}
__device__ __forceinline__ void cohS32u(void* p, unsigned int v){
  __hip_atomic_store((unsigned int*)p, v, __ATOMIC_RELAXED, __HIP_MEMORY_SCOPE_AGENT);
}
__device__ __forceinline__ unsigned short h2u(float f){
  union { _Float16 h; unsigned short u; } c; c.h = (_Float16)f; return c.u;
}
__device__ __forceinline__ unsigned long long pk4h(float a, float b, float c, float d){
  return (unsigned long long)h2u(a) | ((unsigned long long)h2u(b)<<16)
       | ((unsigned long long)h2u(c)<<32) | ((unsigned long long)h2u(d)<<48);
}
__device__ __forceinline__ unsigned int pk2h(float a, float b){
  return (unsigned int)h2u(a) | ((unsigned int)h2u(b)<<16);
}

// ---- flags: producers post own flag; consumers poll relaxed. NO hardware
// fence: all inter-step data lives in t-rotated write-once buffers, so the
// consumer's first touch is a compulsory miss that fetches post-store data.
// (Rotation is DESCENDING in address so stream-prefetch can only run into
// already-consumed slots.)
__device__ __forceinline__ int ldF(int* p){
  return __hip_atomic_load(p, __ATOMIC_RELAXED, __HIP_MEMORY_SCOPE_AGENT);
}
__device__ __forceinline__ void stF(int* p, int v){
  __hip_atomic_store(p, v, __ATOMIC_RELAXED, __HIP_MEMORY_SCOPE_AGENT);
}
__device__ __forceinline__ void post(int* flagArr, int idx, int epoch){
  __syncthreads();   // drain this WG's write-through stores (vmcnt)
  if (threadIdx.x == 0) stF(flagArr + idx*FS, epoch);
}
__device__ __forceinline__ void flagWaitIdx(int* flagArr, int myIdx, bool active, int epoch)
{
  if (active) {
    int* p = flagArr + myIdx*FS;
    while (ldF(p) < epoch) __builtin_amdgcn_s_sleep(1);
  }
  __syncthreads();
  __atomic_signal_fence(__ATOMIC_SEQ_CST);   // no compiler hoist of data loads
}

// ---- stage a [nrows][ncols] fp16 tile into LDS with XOR-16B swizzle ----
__device__ __forceinline__ void stageW(char* dst, const _Float16* __restrict__ src,
                                       int srcld, int nrows, int ncols, int tid)
{
  const int nch = ncols >> 3;
  for (int i = tid; i < nrows*nch; i += 256) {
    int row = i / nch, c = i - row*nch;
    *(f16x8*)(dst + row*ncols*2 + ((c*16) ^ ((row&7)<<4))) =
        *(const f16x8*)(src + (size_t)row*srcld + c*8);
  }
}

// 64x16 MFMA tile: acc += A[64][K](plain cached) @ B[16][K](LDS swizzled)^T
template<int K>
__device__ __forceinline__ void mm16L(f32x4 (&acc)[4],
    const _Float16* __restrict__ A, int lda,
    const char* ldsB, int rowbytes, int koffB, int lane)
{
  const int r = lane & 15, q = lane >> 4;
  const _Float16* a0 = A + r*lda + q*8;
  const char* b0 = ldsB + r*rowbytes + koffB;
  const int sw = (r & 7) << 4;
#pragma unroll
  for (int g = 0; g < K/256; ++g) {
    f16x8 av[8][4], bv[8];
#pragma unroll
    for (int s = 0; s < 8; ++s) {
      int sl = g*8 + s;
      bv[s] = *(const f16x8*)(b0 + ((sl*64 + q*16) ^ sw));
#pragma unroll
      for (int m = 0; m < 4; ++m)
        av[s][m] = *(const f16x8*)(a0 + m*16*lda + sl*32);
    }
#pragma unroll
    for (int s = 0; s < 8; ++s)
#pragma unroll
      for (int m = 0; m < 4; ++m)
        acc[m] = __builtin_amdgcn_mfma_f32_16x16x32_f16(av[s][m], bv[s], acc[m], 0, 0, 0);
  }
}

// ---------------- prep kernels ----------------
__global__ void cvt16s(const float* __restrict__ src, _Float16* __restrict__ dst,
                       int rows, int sld, int scols, int dcols)
{
  int idx = blockIdx.x*256 + threadIdx.x;
  if (idx >= rows*dcols) return;
  int c = idx % dcols, rr = idx / dcols;
  dst[idx] = (c < scols) ? (_Float16)src[(size_t)rr*sld + c] : (_Float16)0.f;
}

// n x n fp32 -> fp16 transpose (for wi^T used by the eq GEMM)
__global__ void cvt16t(const float* __restrict__ src, _Float16* __restrict__ dst, int n)
{
  int idx = blockIdx.x*256 + threadIdx.x;
  if (idx >= n*n) return;
  int rr = idx / n, c = idx - rr*n;
  dst[(size_t)c*n + rr] = (_Float16)src[idx];
}

__global__ void addb(const float* __restrict__ a, const float* __restrict__ b,
                     float* __restrict__ o, int n)
{
  int i = blockIdx.x*256 + threadIdx.x;
  if (i < n) o[i] = a[i] + b[i];
}

__global__ void k_embed(const int* __restrict__ src, const int* __restrict__ trg,
                        const float* __restrict__ eemb, const float* __restrict__ demb,
                        _Float16* __restrict__ x_h, _Float16* __restrict__ xrev_h,
                        _Float16* __restrict__ pe_h)
{
  int idx = blockIdx.x*256 + threadIdx.x;
  const int tot1 = TSRC*NB*EMBP;
  const int tot2 = TDEC*NB*EMBP;
  if (idx < tot1) {
    int e = idx % EMBP, rb = idx / EMBP;
    int t = rb >> 6, b = rb & 63;
    float v = 0.f;
    if (e < EMBD) v = eemb[(size_t)src[rb]*EMBD + e];
    _Float16 hv = (_Float16)v;
    x_h[idx] = hv;
    xrev_h[(size_t)((TSRC-1-t)*NB + b)*EMBP + e] = hv;
  } else if (idx < tot1 + tot2) {
    int k = idx - tot1;
    int e = k % EMBP, rb = k / EMBP;
    float v = 0.f;
    if (e < EMBD) v = demb[(size_t)trg[rb]*EMBD + e];
    pe_h[k] = (_Float16)v;
  }
}

// ---------------- big tiled GEMM (throughput path), fp16 in / f32 out ----------------
__global__ __launch_bounds__(256) void gemm128(
    const _Float16* __restrict__ A, int lda,
    const _Float16* __restrict__ W, int ldw,
    const float* __restrict__ bias,
    float* __restrict__ out, int ldo,
    int K, int mvalid, int nvalid, int rowoff)
{
  __shared__ _Float16 As[128*64];
  __shared__ _Float16 Bs[128*64];
  const int tid = threadIdx.x;
  const int m0 = blockIdx.y*128, n0 = blockIdx.x*128;
  const int w = tid >> 6, lane = tid & 63, r = lane & 15, q = lane >> 4;
  const int mw = (w >> 1)*64, nw = (w & 1)*64;
  f32x4 acc[4][4];
#pragma unroll
  for (int mi=0; mi<4; ++mi)
#pragma unroll
    for (int ni=0; ni<4; ++ni) acc[mi][ni] = 0.f;

  for (int kt = 0; kt < K; kt += 64) {
    f16x8 ra[4], rb[4];
#pragma unroll
    for (int j = 0; j < 4; ++j) {
      int c = j*256 + tid, row = c >> 3, cc = c & 7;
      ra[j] = *(const f16x8*)(A + (size_t)(m0+row)*lda + kt + cc*8);
      rb[j] = *(const f16x8*)(W + (size_t)(n0+row)*ldw + kt + cc*8);
    }
    __syncthreads();
#pragma unroll
    for (int j = 0; j < 4; ++j) {
      int c = j*256 + tid, row = c >> 3, cc = c & 7;
      int sw = cc ^ (row & 7);
      *(f16x8*)((char*)As + row*128 + (sw<<4)) = ra[j];
      *(f16x8*)((char*)Bs + row*128 + (sw<<4)) = rb[j];
    }
    __syncthreads();
#pragma unroll
    for (int kk = 0; kk < 64; kk += 32) {
      int ch = (kk >> 3) + q;
      f16x8 av[4], bv[4];
#pragma unroll
      for (int mi=0; mi<4; ++mi) {
        int row = mw + mi*16 + r;
        av[mi] = *(const f16x8*)((char*)As + row*128 + ((ch ^ (row&7))<<4));
      }
#pragma unroll
      for (int ni=0; ni<4; ++ni) {
        int row = nw + ni*16 + r;
        bv[ni] = *(const f16x8*)((char*)Bs + row*128 + ((ch ^ (row&7))<<4));
      }
#pragma unroll
      for (int mi=0; mi<4; ++mi)
#pragma unroll
        for (int ni=0; ni<4; ++ni)
          acc[mi][ni] = __builtin_amdgcn_mfma_f32_16x16x32_f16(av[mi], bv[ni], acc[mi][ni], 0,0,0);
    }
  }
#pragma unroll
  for (int mi=0; mi<4; ++mi)
#pragma unroll
    for (int ni=0; ni<4; ++ni)
#pragma unroll
      for (int e=0; e<4; ++e) {
        int mrow = m0 + mw + mi*16 + q*4 + e;
        int col  = n0 + nw + ni*16 + r;
        if (mrow < mvalid && col < nvalid)
          out[(size_t)(mrow + rowoff)*ldo + col] = acc[mi][ni][e] + bias[col];
      }
}

// same GEMM but fp16 output (for eq and peproj)
__global__ __launch_bounds__(256) void gemm128h(
    const _Float16* __restrict__ A, int lda,
    const _Float16* __restrict__ W, int ldw,
    const float* __restrict__ bias,
    _Float16* __restrict__ out, int ldo,
    int K, int mvalid, int nvalid)
{
  __shared__ _Float16 As[128*64];
  __shared__ _Float16 Bs[128*64];
  const int tid = threadIdx.x;
  const int m0 = blockIdx.y*128, n0 = blockIdx.x*128;
  const int w = tid >> 6, lane = tid & 63, r = lane & 15, q = lane >> 4;
  const int mw = (w >> 1)*64, nw = (w & 1)*64;
  f32x4 acc[4][4];
#pragma unroll
  for (int mi=0; mi<4; ++mi)
#pragma unroll
    for (int ni=0; ni<4; ++ni) acc[mi][ni] = 0.f;

  for (int kt = 0; kt < K; kt += 64) {
    f16x8 ra[4], rb[4];
#pragma unroll
    for (int j = 0; j < 4; ++j) {
      int c = j*256 + tid, row = c >> 3, cc = c & 7;
      ra[j] = *(const f16x8*)(A + (size_t)(m0+row)*lda + kt + cc*8);
      rb[j] = *(const f16x8*)(W + (size_t)(n0+row)*ldw + kt + cc*8);
    }
    __syncthreads();
#pragma unroll
    for (int j = 0; j < 4; ++j) {
      int c = j*256 + tid, row = c >> 3, cc = c & 7;
      int sw = cc ^ (row & 7);
      *(f16x8*)((char*)As + row*128 + (sw<<4)) = ra[j];
      *(f16x8*)((char*)Bs + row*128 + (sw<<4)) = rb[j];
    }
    __syncthreads();
#pragma unroll
    for (int kk = 0; kk < 64; kk += 32) {
      int ch = (kk >> 3) + q;
      f16x8 av[4], bv[4];
#pragma unroll
      for (int mi=0; mi<4; ++mi) {
        int row = mw + mi*16 + r;
        av[mi] = *(const f16x8*)((char*)As + row*128 + ((ch ^ (row&7))<<4));
      }
#pragma unroll
      for (int ni=0; ni<4; ++ni) {
        int row = nw + ni*16 + r;
        bv[ni] = *(const f16x8*)((char*)Bs + row*128 + ((ch ^ (row&7))<<4));
      }
#pragma unroll
      for (int mi=0; mi<4; ++mi)
#pragma unroll
        for (int ni=0; ni<4; ++ni)
          acc[mi][ni] = __builtin_amdgcn_mfma_f32_16x16x32_f16(av[mi], bv[ni], acc[mi][ni], 0,0,0);
    }
  }
#pragma unroll
  for (int mi=0; mi<4; ++mi)
#pragma unroll
    for (int ni=0; ni<4; ++ni)
#pragma unroll
      for (int e=0; e<4; ++e) {
        int mrow = m0 + mw + mi*16 + q*4 + e;
        int col  = n0 + nw + ni*16 + r;
        if (mrow < mvalid && col < nvalid)
          out[(size_t)mrow*ldo + col] = (_Float16)(acc[mi][ni][e] + bias[col]);
      }
}

// ---------------- persistent encoder (64 WGs, 1 hop/step, rotated h) ----------------
struct EA {
  const _Float16 *whhF, *whhR;   // [2048][512]
  const float *xpF, *xpR;        // [50*64][2048] (bias folded)
  _Float16 *h;                   // [TSRC+1 slots][2 dir][64][512]; slot TSRC zeroed
  _Float16 *enc_out;             // [50][64][1024]
  _Float16 *dh0;                 // dh slot TDEC (decoder handoff)
  float *dc;                     // [64][1024]
  int *flags;                    // 64
};

__global__ __launch_bounds__(256, 1) void enc_seq(EA a)
{
  extern __shared__ char lds[];
  const int tid = threadIdx.x, w = tid >> 6, lane = tid & 63;
  const int wgid = blockIdx.x;
  const int r = lane & 15, q4 = lane >> 4;
  float (*sm4)[64][16] = (float(*)[64][16])(lds + 65536);

  const int dir = wgid >> 5, j0 = (wgid & 31) << 4;
  const _Float16* whh = dir ? a.whhR : a.whhF;
  for (int g = 0; g < 4; ++g)
    stageW(lds + g*16384, whh + (size_t)(g*EH + j0)*EH, EH, 16, 512, tid);
  __syncthreads();

  const int b = tid >> 2, jq = (tid & 3) * 4;
  float creg[4] = {0.f, 0.f, 0.f, 0.f};
  const float* xpbase = dir ? a.xpR : a.xpF;

  for (int t = 0; t < TSRC; ++t) {
    float xr[4][4];
#pragma unroll
    for (int g = 0; g < 4; ++g)
#pragma unroll
      for (int k = 0; k < 4; ++k)
        xr[g][k] = xpbase[((size_t)t*NB + b)*2048 + g*EH + j0 + jq + k];
    if (t) flagWaitIdx(a.flags, dir*32 + tid, tid < 32, t);
    // descending rotation: read slot (TSRC-t), write slot (TSRC-1-t)
    const _Float16* H = a.h + ((size_t)(TSRC-t)*2 + dir)*NB*EH;
    f32x4 acc[4];
#pragma unroll
    for (int m=0;m<4;++m) acc[m] = 0.f;
    mm16L<EH>(acc, H, EH, lds + w*16384, 1024, 0, lane);
#pragma unroll
    for (int m=0;m<4;++m)
#pragma unroll
      for (int e=0;e<4;++e) sm4[w][m*16 + q4*4 + e][r] = acc[m][e];
    __syncthreads();
    _Float16* Ho = a.h + ((size_t)(TSRC-1-t)*2 + dir)*NB*EH;
    const int erow = dir ? (TSRC-1 - t) : t;
    float hv[4];
#pragma unroll
    for (int k = 0; k < 4; ++k) {
      int jj = jq + k;
      float gi = sm4[0][b][jj] + xr[0][k];
      float gf = sm4[1][b][jj] + xr[1][k];
      float gg = sm4[2][b][jj] + xr[2][k];
      float go = sm4[3][b][jj] + xr[3][k];
      float cn = sigm(gf)*creg[k] + sigm(gi)*tanhf(gg);
      creg[k] = cn;
      hv[k] = sigm(go)*tanhf(cn);
    }
    cohS64(Ho + b*EH + j0 + jq, pk4h(hv[0],hv[1],hv[2],hv[3]));
    cohS64(a.enc_out + ((size_t)erow*NB + b)*DH + dir*EH + j0 + jq, pk4h(hv[0],hv[1],hv[2],hv[3]));
    if (t == TSRC-1) {
#pragma unroll
      for (int k = 0; k < 4; ++k) {
        int j = j0 + jq + k;
        cohS16(a.dh0 + b*DH + 2*j + dir, (_Float16)hv[k]);
        cohS32(a.dc + b*DH + 2*j + dir, creg[k]);
      }
    }
    post(a.flags, wgid, t+1);
  }
}

// ---------------- persistent decoder (224 WGs, 3 hops/step, rotated dh/st/ct) ----------------
// roles: 0-63 P2 (attention via precomputed eq) | 64-191 D (dWhh·dh + w3c·ct
// fused, LSTM) | 192-223 C (ct = tanh(wo·[st;dh]), dh-part pre-overlapped)
struct DA {
  const _Float16 *wo;            // [1024][2048]
  const _Float16 *wdh;           // [4096][1024] dec_Whh
  const _Float16 *w3c;           // [4096][1024] dWih ct-part
  const _Float16 *eq;            // [3200][1024] enc_out @ wi (fp16)
  const _Float16 *enc_out;       // [50][64][1024]
  const _Float16 *pp;            // [49*64][4096] pe-proj + biases (fp16)
  _Float16 *dh;                  // [TDEC+1 slots][64][1024]; slot TDEC = enc handoff
  float *dc;                     // [64][1024] (enc handoff)
  _Float16 *st, *ct;             // [TDEC+1 slots][64][1024]
  _Float16 *hdec;                // [3200][1024]
  int *flags;                    // FB 64 | FC 32 | FD 128
};

__global__ __launch_bounds__(256, 1) void dec_seq(DA a)
{
  extern __shared__ char lds[];
  const int tid = threadIdx.x, w = tid >> 6, lane = tid & 63;
  const int wgid = blockIdx.x;
  const int r = lane & 15, q4 = lane >> 4;
  float (*sm4)[64][16] = (float(*)[64][16])(lds + LDS_SCR);
  float* qs = (float*)(lds + LDS_SCR);           // P2 dh row (aliases sm4)
  float* sc = (float*)(lds + LDS_SCR + 16384);

  int* FB = a.flags;
  int* FC = FB + 64*FS;
  int* FD = FC + 32*FS;

  // ---- stage weights ----
  if (wgid >= 64 && wgid < 192) {
    int i = wgid - 64;
    for (int g = 0; g < 4; ++g)
      stageW(lds + g*8*2048, a.wdh + (size_t)(g*1024 + i*8)*DH, DH, 8, 1024, tid);
    for (int g = 0; g < 4; ++g)
      stageW(lds + 65536 + g*8*2048, a.w3c + (size_t)(g*1024 + i*8)*DH, DH, 8, 1024, tid);
  } else if (wgid >= 192) {
    int i = wgid - 192;
    stageW(lds,         a.wo + (size_t)i*32*2048,        2048, 32, 1024, tid);  // st-part
    stageW(lds + 65536, a.wo + (size_t)i*32*2048 + 1024, 2048, 32, 1024, tid);  // dh-part
  }
  __syncthreads();

  const bool isP2 = (wgid < 64);
  const bool isD  = (wgid >= 64 && wgid < 192);
  const bool isC  = (wgid >= 192);

  float dcreg[2] = {0.f, 0.f};

  for (int t = 0; t < TDEC; ++t) {
    // descending rotation: state in slot (TDEC-t); new state to slot (TDEC-1-t)
    const size_t cur = (size_t)(TDEC - t)*NB*DH;
    const size_t nxt = (size_t)(TDEC - 1 - t)*NB*DH;
    const _Float16* dhC = a.dh + cur;

    // ---- P2: scores = eq·dh, softmax, st (one batch element per WG) ----
    if (isP2) {
      if (t) flagWaitIdx(FD, tid, tid < 128, t);
      const int b = wgid;
      if (tid < 128) {
        f16x8 v = *(const f16x8*)(dhC + b*DH + tid*8);
#pragma unroll
        for (int k = 0; k < 8; ++k) qs[tid*8 + k] = (float)v[k];
      }
      __syncthreads();
      for (int tt = w; tt < TSRC; tt += 4) {
        const _Float16* er = a.eq + ((size_t)tt*NB + b)*DH + lane*16;
        const float* qq = qs + lane*16;
        f16x8 e0 = *(const f16x8*)(er);
        f16x8 e1 = *(const f16x8*)(er + 8);
        float s = 0.f;
#pragma unroll
        for (int ii=0; ii<8; ++ii) s += (float)e0[ii]*qq[ii];
#pragma unroll
        for (int ii=0; ii<8; ++ii) s += (float)e1[ii]*qq[8+ii];
#pragma unroll
        for (int o=32; o; o>>=1) s += __shfl_xor(s, o);
        if (lane == 0) sc[tt] = s;
      }
      __syncthreads();
      float mx = -1e30f;
      for (int tt=0; tt<TSRC; ++tt) mx = fmaxf(mx, sc[tt]);
      __syncthreads();
      if (tid < TSRC) sc[tid] = expf(sc[tid] - mx);
      __syncthreads();
      float s50 = 0.f;
      for (int tt=0; tt<TSRC; ++tt) s50 += sc[tt];
      const float inv = 1.f/s50;
      const int c0 = tid*4;
      float a0=0.f, a1=0.f, a2=0.f, a3=0.f;
      for (int tt=0; tt<TSRC; ++tt) {
        float wt = sc[tt];
        const _Float16* er = a.enc_out + ((size_t)tt*NB + b)*DH + c0;
        a0 += wt*(float)er[0]; a1 += wt*(float)er[1];
        a2 += wt*(float)er[2]; a3 += wt*(float)er[3];
      }
      cohS64(a.st + cur + b*DH + c0, pk4h(a0*inv, a1*inv, a2*inv, a3*inv));
      post(FB, wgid, t+1);
    }

    // ---- C: ct = tanh(wo_st·st + wo_dh·dh); dh-part overlapped with P2 ----
    if (isC) {
      if (t) flagWaitIdx(FD, tid, tid < 128, t);
      const int i = wgid - 192, col0 = i*32;
      const int cs = w >> 1, kh = w & 1;
      f32x4 acc[4];
#pragma unroll
      for (int m=0;m<4;++m) acc[m] = 0.f;
      mm16L<512>(acc, dhC + kh*512, DH, lds + 65536 + cs*16*2048, 2048, kh*1024, lane);
      flagWaitIdx(FB, tid, tid < 64, t+1);
      mm16L<512>(acc, a.st + cur + kh*512, DH, lds + cs*16*2048, 2048, kh*1024, lane);
#pragma unroll
      for (int m=0;m<4;++m)
#pragma unroll
        for (int e=0;e<4;++e) sm4[w][m*16 + q4*4 + e][r] = acc[m][e];
      __syncthreads();
      const int b = tid >> 2, cc0 = (tid & 3)*8;
      float v[8];
#pragma unroll
      for (int k = 0; k < 8; ++k) {
        int cc = cc0 + k;
        v[k] = tanhf(sm4[(cc>>4)*2][b][cc&15] + sm4[(cc>>4)*2+1][b][cc&15]);
      }
      cohS64(a.ct + cur + b*DH + col0 + cc0,     pk4h(v[0],v[1],v[2],v[3]));
      cohS64(a.ct + cur + b*DH + col0 + cc0 + 4, pk4h(v[4],v[5],v[6],v[7]));
      post(FC, i, t+1);
    }

    // ---- D: gates = dWhh·dh (after FD) + w3c·ct (after FC) + pp; LSTM ----
    if (isD) {
      const int i = wgid - 64;
      if (t) flagWaitIdx(FD, tid, tid < 128, t);
      const int b = tid >> 2, j0 = i*8, jj2 = (tid & 3)*2;
      if (t == 0) {
        dcreg[0] = a.dc[b*DH + j0 + jj2];
        dcreg[1] = a.dc[b*DH + j0 + jj2 + 1];
      }
      const int cs = w >> 1, kh = w & 1;
      f32x4 acc[4];
#pragma unroll
      for (int m=0;m<4;++m) acc[m] = 0.f;
      mm16L<512>(acc, dhC + kh*512, DH, lds + cs*16*2048, 2048, kh*1024, lane);
      // prefetch pp (read-only, L2-warm) before the FC wait
      float ppv[4][2];
#pragma unroll
      for (int g = 0; g < 4; ++g)
#pragma unroll
        for (int k = 0; k < 2; ++k)
          ppv[g][k] = (float)a.pp[((size_t)t*NB + b)*4096 + g*DH + j0 + jj2 + k];
      flagWaitIdx(FC, tid, tid < 32, t+1);
      mm16L<512>(acc, a.ct + cur + kh*512, DH, lds + 65536 + cs*16*2048, 2048, kh*1024, lane);
#pragma unroll
      for (int m=0;m<4;++m)
#pragma unroll
        for (int e=0;e<4;++e) sm4[w][m*16 + q4*4 + e][r] = acc[m][e];
      __syncthreads();
      float hv[2];
#pragma unroll
      for (int k = 0; k < 2; ++k) {
        int jj = jj2 + k;
        float gi = sm4[0][b][jj]   + sm4[1][b][jj]   + ppv[0][k];
        float gf = sm4[0][b][8+jj] + sm4[1][b][8+jj] + ppv[1][k];
        float gg = sm4[2][b][jj]   + sm4[3][b][jj]   + ppv[2][k];
        float go = sm4[2][b][8+jj] + sm4[3][b][8+jj] + ppv[3][k];
        float cn = sigm(gf)*dcreg[k] + sigm(gi)*tanhf(gg);
        dcreg[k] = cn;
        hv[k] = sigm(go)*tanhf(cn);
      }
      cohS32u(a.dh + nxt + b*DH + j0 + jj2, pk2h(hv[0], hv[1]));
      cohS32u(a.hdec + ((size_t)t*NB + b)*DH + j0 + jj2, pk2h(hv[0], hv[1]));
      post(FD, i, t+1);
    }
  }
}

// ---------------- in-place log-softmax (online max+sum, 2 reads + 1 write) ----------------
__global__ __launch_bounds__(256) void lsm(float* __restrict__ out)
{
  const int row = NB + blockIdx.x;
  float* p = out + (size_t)row*GV;
  const int tid = threadIdx.x;
  __shared__ float rm[4], rl[4];
  float m = -1e30f, l = 0.f;
  for (int i = tid; i < GV; i += 256) {
    float v = p[i];
    float M = fmaxf(m, v);
    l = l*expf(m - M) + expf(v - M);
    m = M;
  }
  for (int off=32; off; off>>=1) {
    float m2 = __shfl_down(m, off), l2 = __shfl_down(l, off);
    float M = fmaxf(m, m2);
    l = l*expf(m - M) + l2*expf(m2 - M);
    m = M;
  }
  if ((tid & 63) == 0) { rm[tid>>6] = m; rl[tid>>6] = l; }
  __syncthreads();
  m = rm[0]; l = rl[0];
#pragma unroll
  for (int k=1; k<4; ++k) {
    float M = fmaxf(m, rm[k]);
    l = l*expf(m - M) + rl[k]*expf(rm[k] - M);
    m = M;
  }
  float lse = m + logf(l);
  for (int i = tid; i < GV; i += 256) p[i] -= lse;
}

// ---------------- host ----------------
extern "C" void kernel_launch(void* const* d_in, const int* in_sizes, int n_in,
                              void* d_out, int out_size, void* d_ws, size_t ws_size,
                              hipStream_t stream)
{
  const int*   src  = (const int*)d_in[0];
  const int*   trg  = (const int*)d_in[1];
  const float* WihF = (const float*)d_in[2];
  const float* WhhF = (const float*)d_in[3];
  const float* bihF = (const float*)d_in[4];
  const float* bhhF = (const float*)d_in[5];
  const float* WihR = (const float*)d_in[6];
  const float* WhhR = (const float*)d_in[7];
  const float* bihR = (const float*)d_in[8];
  const float* bhhR = (const float*)d_in[9];
  const float* dWih = (const float*)d_in[10];
  const float* dWhh = (const float*)d_in[11];
  const float* dbih = (const float*)d_in[12];
  const float* dbhh = (const float*)d_in[13];
  const float* eemb = (const float*)d_in[14];
  const float* demb = (const float*)d_in[15];
  const float* wi   = (const float*)d_in[16];
  const float* wo   = (const float*)d_in[17];
  const float* genw = (const float*)d_in[18];
  const float* genb = (const float*)d_in[19];
  float* out = (float*)d_out;

  char* ws = (char*)d_ws;
  size_t off = 0;
  auto alloc = [&](size_t bytes)->char* {
    char* p = ws + off; off = (off + bytes + 255) & ~(size_t)255; return p;
  };
  _Float16* x_h    = (_Float16*)alloc((size_t)TSRC*NB*EMBP*2);
  _Float16* xrev_h = (_Float16*)alloc((size_t)TSRC*NB*EMBP*2);
  _Float16* pe_h   = (_Float16*)alloc((size_t)TDEC*NB*EMBP*2);
  _Float16* wihF_h = (_Float16*)alloc((size_t)2048*EMBP*2);
  _Float16* wihR_h = (_Float16*)alloc((size_t)2048*EMBP*2);
  _Float16* whhF_h = (_Float16*)alloc((size_t)2048*EH*2);
  _Float16* whhR_h = (_Float16*)alloc((size_t)2048*EH*2);
  _Float16* wdh_h  = (_Float16*)alloc((size_t)4096*DH*2);
  _Float16* wo_h   = (_Float16*)alloc((size_t)DH*2048*2);
  _Float16* w3c    = (_Float16*)alloc((size_t)4096*DH*2);
  _Float16* w3pe   = (_Float16*)alloc((size_t)4096*EMBP*2);
  _Float16* wiT_h  = (_Float16*)alloc((size_t)DH*DH*2);
  _Float16* genw_h = (_Float16*)alloc((size_t)GVP*DH*2);
  float* b4f   = (float*)alloc(2048*4);
  float* b4r   = (float*)alloc(2048*4);
  float* db4   = (float*)alloc(4096*4);
  float* zb    = (float*)alloc(DH*4);
  float* xp_f  = (float*)alloc((size_t)TSRC*NB*2048*4);
  float* xp_r  = (float*)alloc((size_t)TSRC*NB*2048*4);
  _Float16* peproj = (_Float16*)alloc((size_t)TDEC*NB*4096*2);
  _Float16* enc_out = (_Float16*)alloc((size_t)TSRC*NB*DH*2);
  _Float16* eq_h = (_Float16*)alloc((size_t)TSRC*NB*DH*2);
  _Float16* hbuf = (_Float16*)alloc((size_t)(TSRC+1)*2*NB*EH*2);
  _Float16* dh = (_Float16*)alloc((size_t)(TDEC+1)*NB*DH*2);
  float* dc = (float*)alloc((size_t)NB*DH*4);
  _Float16* st = (_Float16*)alloc((size_t)(TDEC+1)*NB*DH*2);
  _Float16* ct = (_Float16*)alloc((size_t)(TDEC+1)*NB*DH*2);
  _Float16* hdec = (_Float16*)alloc((size_t)3200*DH*2);
  int* eflags = (int*)alloc(64*FS*4);
  int* dflags = (int*)alloc(224*FS*4);
  (void)in_sizes; (void)n_in; (void)out_size; (void)ws_size;

  // --- init / zero state (graph replays don't re-poison) ---
  hipMemsetAsync(hbuf + (size_t)TSRC*2*NB*EH, 0, (size_t)2*NB*EH*2, stream);  // h slot TSRC
  hipMemsetAsync(hdec + (size_t)3136*DH, 0, (size_t)64*DH*2, stream);
  hipMemsetAsync(genw_h + (size_t)GV*DH, 0, (size_t)(GVP-GV)*DH*2, stream);
  hipMemsetAsync(out, 0, (size_t)NB*GV*4, stream);
  hipMemsetAsync(zb, 0, DH*4, stream);
  hipMemsetAsync(eflags, 0, 64*FS*4, stream);
  hipMemsetAsync(dflags, 0, 224*FS*4, stream);

  auto cgrid = [](size_t n){ return dim3((unsigned)((n + 255)/256)); };

  // --- weight conversion (fp16) ---
  cvt16s<<<cgrid((size_t)2048*EMBP),256,0,stream>>>(WihF, wihF_h, 2048, EMBD, EMBD, EMBP);
  cvt16s<<<cgrid((size_t)2048*EMBP),256,0,stream>>>(WihR, wihR_h, 2048, EMBD, EMBD, EMBP);
  cvt16s<<<cgrid((size_t)2048*EH),256,0,stream>>>(WhhF, whhF_h, 2048, EH, EH, EH);
  cvt16s<<<cgrid((size_t)2048*EH),256,0,stream>>>(WhhR, whhR_h, 2048, EH, EH, EH);
  cvt16s<<<cgrid((size_t)4096*DH),256,0,stream>>>(dWhh, wdh_h, 4096, DH, DH, DH);
  cvt16s<<<cgrid((size_t)DH*2048),256,0,stream>>>(wo, wo_h, DH, 2048, 2048, 2048);
  cvt16s<<<cgrid((size_t)4096*DH),256,0,stream>>>(dWih, w3c, 4096, 1324, 1024, 1024);
  cvt16s<<<cgrid((size_t)4096*EMBP),256,0,stream>>>(dWih + 1024, w3pe, 4096, 1324, 300, EMBP);
  cvt16t<<<cgrid((size_t)DH*DH),256,0,stream>>>(wi, wiT_h, DH);
  cvt16s<<<cgrid((size_t)GV*DH),256,0,stream>>>(genw, genw_h, GV, DH, DH, DH);
  addb<<<cgrid(2048),256,0,stream>>>(bihF, bhhF, b4f, 2048);
  addb<<<cgrid(2048),256,0,stream>>>(bihR, bhhR, b4r, 2048);
  addb<<<cgrid(4096),256,0,stream>>>(dbih, dbhh, db4, 4096);
  k_embed<<<cgrid((size_t)(TSRC+TDEC)*NB*EMBP),256,0,stream>>>(src, trg, eemb, demb, x_h, xrev_h, pe_h);

  // --- input projections ---
  gemm128<<<dim3(16,25),256,0,stream>>>(x_h,    EMBP, wihF_h, EMBP, b4f, xp_f, 2048, EMBP, 3200, 2048, 0);
  gemm128<<<dim3(16,25),256,0,stream>>>(xrev_h, EMBP, wihR_h, EMBP, b4r, xp_r, 2048, EMBP, 3200, 2048, 0);
  gemm128h<<<dim3(32,25),256,0,stream>>>(pe_h, EMBP, w3pe, EMBP, db4, peproj, 4096, EMBP, 3136, 4096);

  // --- encoder (persistent, 64 WGs) ---
  EA ea;
  ea.whhF = whhF_h; ea.whhR = whhR_h;
  ea.xpF = xp_f; ea.xpR = xp_r;
  ea.h = hbuf; ea.enc_out = enc_out;
  ea.dh0 = dh + (size_t)TDEC*NB*DH;   // dh slot TDEC = decoder initial state
  ea.dc = dc;
  ea.flags = eflags;
  hipFuncSetAttribute((const void*)enc_seq,
                      hipFuncAttributeMaxDynamicSharedMemorySize, LDS_ENC);
  enc_seq<<<dim3(64), 256, LDS_ENC, stream>>>(ea);

  // --- eq = enc_out @ wi  (kills the decoder's q phase/hop) ---
  gemm128h<<<dim3(8,25),256,0,stream>>>(enc_out, DH, wiT_h, DH, zb, eq_h, DH, DH, 3200, DH);

  // --- decoder (persistent, 224 WGs, 3 hops/step) ---
  DA da;
  da.wo = wo_h; da.wdh = wdh_h; da.w3c = w3c;
  da.eq = eq_h; da.enc_out = enc_out;
  da.pp = peproj;
  da.dh = dh; da.dc = dc;
  da.st = st; da.ct = ct;
  da.hdec = hdec;
  da.flags = dflags;
  hipFuncSetAttribute((const void*)dec_seq,
                      hipFuncAttributeMaxDynamicSharedMemorySize, LDS_TOT);
  dec_seq<<<dim3(224), 256, LDS_TOT, stream>>>(da);

  // --- generator + log-softmax ---
  gemm128<<<dim3(GVP/128,25),256,0,stream>>>(hdec, DH, genw_h, DH, genb, out, GV, DH, 3136, GV, NB);
  lsm<<<3136,256,0,stream>>>(out);
}